// Round 1
// baseline (7342.453 us; speedup 1.0000x reference)
//
#include <hip/hip_runtime.h>

// Problem constants (match reference)
constexpr int Bv = 8;
constexpr int Nv = 2048;
constexpr int Hv = 4;
constexpr int Dv = 64;
constexpr int OUTv = 256;
constexpr int HD = Hv * Dv;          // 256
constexpr size_t PH = (size_t)Bv * Hv * Nv * Dv;  // 4,194,304 elements per Q/K/V/O buffer

// ---------------------------------------------------------------------------
// Kernel 1: per-head QKV projection. One block per token (b,n), 256 threads:
// thread t -> head h = t/64, out-dim e = t%64. Scale 1/sqrt(D)=0.125 folded
// into Q at store. Output layout [B][H][N][D].
// ---------------------------------------------------------------------------
__global__ __launch_bounds__(256) void qkv_kernel(
    const float* __restrict__ x,
    const float* __restrict__ Wq, const float* __restrict__ Wk, const float* __restrict__ Wv,
    const float* __restrict__ bq, const float* __restrict__ bk, const float* __restrict__ bv,
    float* __restrict__ Q, float* __restrict__ K, float* __restrict__ V)
{
    const int token = blockIdx.x;            // b*N + n
    const int t = threadIdx.x;               // 0..255
    const int h = t >> 6, e = t & 63;

    __shared__ __align__(16) float xs[HD];
    xs[t] = x[(size_t)token * HD + t];
    __syncthreads();

    const float* xh = xs + h * Dv;
    const float* wq = Wq + (size_t)h * Dv * Dv + e;
    const float* wk = Wk + (size_t)h * Dv * Dv + e;
    const float* wv = Wv + (size_t)h * Dv * Dv + e;

    float q = 0.f, k = 0.f, v = 0.f;
#pragma unroll
    for (int d = 0; d < Dv; ++d) {
        const float xv = xh[d];              // LDS broadcast (all lanes same addr)
        q = fmaf(xv, wq[d * Dv], q);         // coalesced over e
        k = fmaf(xv, wk[d * Dv], k);
        v = fmaf(xv, wv[d * Dv], v);
    }
    q = (q + bq[h * Dv + e]) * 0.125f;       // fold 1/sqrt(64) into Q
    k += bk[h * Dv + e];
    v += bv[h * Dv + e];

    const int b_ = token >> 11;              // / N
    const int n_ = token & (Nv - 1);
    const size_t idx = (((size_t)b_ * Hv + h) * Nv + n_) * Dv + e;
    Q[idx] = q; K[idx] = k; V[idx] = v;
}

// ---------------------------------------------------------------------------
// Kernel 2: attention. One block (256 thr) per query row (b,h,n).
// Phase 1: each thread dots q against 8 keys (float4), block softmax reduce,
// P (2048 floats) staged in LDS. Phase 2: P @ V with float4 V reads.
// ---------------------------------------------------------------------------
__global__ __launch_bounds__(256) void attn_kernel(
    const float* __restrict__ Q, const float* __restrict__ K,
    const float* __restrict__ V, float* __restrict__ O)
{
    const int idx = blockIdx.x;              // bh*N + n
    const int n_ = idx & (Nv - 1);
    const int bh = idx >> 11;
    const float* Kp = K + (size_t)bh * Nv * Dv;
    const float* Vp = V + (size_t)bh * Nv * Dv;
    const float* qrow = Q + ((size_t)bh * Nv + n_) * Dv;

    const int t = threadIdx.x;
    const int lane = t & 63, wave = t >> 6;

    __shared__ __align__(16) float qs[Dv];
    __shared__ float p[Nv];                  // 8 KB
    __shared__ float red1[4], red2[4];
    __shared__ __align__(16) float ored[16 * Dv];  // 4 KB

    if (t < Dv) qs[t] = qrow[t];
    __syncthreads();

    const float4* qs4 = reinterpret_cast<const float4*>(qs);

    float s[8];
    float lmax = -1e30f;
#pragma unroll
    for (int j = 0; j < 8; ++j) {
        const float4* kr = reinterpret_cast<const float4*>(Kp + (size_t)(t + j * 256) * Dv);
        float acc = 0.f;
#pragma unroll
        for (int d = 0; d < Dv / 4; ++d) {
            const float4 kv = kr[d];
            const float4 qv = qs4[d];
            acc = fmaf(qv.x, kv.x, acc);
            acc = fmaf(qv.y, kv.y, acc);
            acc = fmaf(qv.z, kv.z, acc);
            acc = fmaf(qv.w, kv.w, acc);
        }
        s[j] = acc;
        lmax = fmaxf(lmax, acc);
    }
    // wave max then cross-wave max
#pragma unroll
    for (int off = 32; off; off >>= 1) lmax = fmaxf(lmax, __shfl_xor(lmax, off, 64));
    if (lane == 0) red1[wave] = lmax;
    __syncthreads();
    const float gmax = fmaxf(fmaxf(red1[0], red1[1]), fmaxf(red1[2], red1[3]));

    float lsum = 0.f;
#pragma unroll
    for (int j = 0; j < 8; ++j) {
        const float e_ = __expf(s[j] - gmax);
        p[t + j * 256] = e_;
        lsum += e_;
    }
#pragma unroll
    for (int off = 32; off; off >>= 1) lsum += __shfl_xor(lsum, off, 64);
    if (lane == 0) red2[wave] = lsum;
    __syncthreads();
    const float inv = 1.0f / (red2[0] + red2[1] + red2[2] + red2[3]);

    // Phase 2: thread t handles dims [e4*4, e4*4+4) over key chunk c of 128.
    const int e4 = t & 15;
    const int c = t >> 4;
    float4 acc4 = make_float4(0.f, 0.f, 0.f, 0.f);
    const float* pv = p + c * 128;
    const float4* vb = reinterpret_cast<const float4*>(Vp + (size_t)c * 128 * Dv) + e4;
    for (int m = 0; m < 128; ++m) {
        const float pm = pv[m];
        const float4 vv = vb[(size_t)m * 16];
        acc4.x = fmaf(pm, vv.x, acc4.x);
        acc4.y = fmaf(pm, vv.y, acc4.y);
        acc4.z = fmaf(pm, vv.z, acc4.z);
        acc4.w = fmaf(pm, vv.w, acc4.w);
    }
    reinterpret_cast<float4*>(ored + c * Dv)[e4] = acc4;
    __syncthreads();
    if (t < Dv) {
        float o = 0.f;
#pragma unroll
        for (int cc = 0; cc < 16; ++cc) o += ored[cc * Dv + t];
        O[((size_t)bh * Nv + n_) * Dv + t] = o * inv;
    }
}

// ---------------------------------------------------------------------------
// Kernel 3: concat heads + final projection. 8 tokens per block, register
// blocked so each Wp element load feeds 8 FMAs.
// ---------------------------------------------------------------------------
__global__ __launch_bounds__(256) void proj_kernel(
    const float* __restrict__ O, const float* __restrict__ Wp,
    const float* __restrict__ bp, float* __restrict__ out)
{
    const int base = blockIdx.x * 8;         // token base
    const int t = threadIdx.x;               // output dim
    __shared__ float os[8 * OUTv];           // 8 KB

#pragma unroll
    for (int i = 0; i < 8; ++i) {
        const int tok = base + i;
        const int b_ = tok >> 11, n_ = tok & (Nv - 1);
        const int h = t >> 6, e = t & 63;
        os[i * OUTv + t] = O[(((size_t)b_ * Hv + h) * Nv + n_) * Dv + e];
    }
    __syncthreads();

    float acc[8];
    const float bias = bp[t];
#pragma unroll
    for (int i = 0; i < 8; ++i) acc[i] = bias;

    for (int c = 0; c < HD; ++c) {
        const float w = Wp[(size_t)c * OUTv + t];   // coalesced
#pragma unroll
        for (int i = 0; i < 8; ++i) acc[i] = fmaf(os[i * OUTv + c], w, acc[i]);
    }
#pragma unroll
    for (int i = 0; i < 8; ++i) out[(size_t)(base + i) * OUTv + t] = acc[i];
}

// ---------------------------------------------------------------------------
extern "C" void kernel_launch(void* const* d_in, const int* in_sizes, int n_in,
                              void* d_out, int out_size, void* d_ws, size_t ws_size,
                              hipStream_t stream)
{
    const float* x  = (const float*)d_in[0];
    const float* Wq = (const float*)d_in[1];
    const float* Wk = (const float*)d_in[2];
    const float* Wv = (const float*)d_in[3];
    const float* bq = (const float*)d_in[4];
    const float* bk = (const float*)d_in[5];
    const float* bv = (const float*)d_in[6];
    const float* Wp = (const float*)d_in[7];
    const float* bp = (const float*)d_in[8];
    float* out = (float*)d_out;

    float* ws = (float*)d_ws;
    float* Q = ws;
    float* K = ws + PH;
    float* V = ws + 2 * PH;
    float* O = ws + 3 * PH;      // 64 MB total fp32 scratch

    qkv_kernel<<<Bv * Nv, 256, 0, stream>>>(x, Wq, Wk, Wv, bq, bk, bv, Q, K, V);
    attn_kernel<<<Bv * Hv * Nv, 256, 0, stream>>>(Q, K, V, O);
    proj_kernel<<<(Bv * Nv) / 8, 256, 0, stream>>>(O, Wp, bp, out);
}

// Round 2
// 409.727 us; speedup vs baseline: 17.9204x; 17.9204x over previous
//
#include <hip/hip_runtime.h>

typedef __attribute__((ext_vector_type(4))) float f32x4;
typedef __attribute__((ext_vector_type(8))) __bf16 bf16x8;
typedef __attribute__((ext_vector_type(8))) short short8;

constexpr int Bv = 8, Nv = 2048, Hv = 4, Dv = 64, OUTv = 256, HD = 256;
constexpr int BH = Bv * Hv;                      // 32
constexpr size_t PH = (size_t)BH * Nv * Dv;      // 4,194,304 bf16 elements per buffer

// round-to-nearest-even fp32 -> bf16 bits
__device__ __forceinline__ unsigned short f2bf(float f) {
    unsigned u = __float_as_uint(f);
    u += 0x7FFFu + ((u >> 16) & 1u);
    return (unsigned short)(u >> 16);
}

// ---------------------------------------------------------------------------
// Kernel 1: QKV projection -> bf16. One block per token, thread t -> (h,e).
// Q pre-scaled by 1/sqrt(64). Layout [bh][n][d].
// ---------------------------------------------------------------------------
__global__ __launch_bounds__(256) void qkv_kernel(
    const float* __restrict__ x,
    const float* __restrict__ Wq, const float* __restrict__ Wk, const float* __restrict__ Wv,
    const float* __restrict__ bq, const float* __restrict__ bk, const float* __restrict__ bv,
    unsigned short* __restrict__ Qb, unsigned short* __restrict__ Kb, unsigned short* __restrict__ Vb)
{
    const int token = blockIdx.x;
    const int t = threadIdx.x;
    const int h = t >> 6, e = t & 63;

    __shared__ __align__(16) float xs[HD];
    xs[t] = x[(size_t)token * HD + t];
    __syncthreads();

    const float* xh = xs + h * Dv;
    const float* wq = Wq + h * Dv * Dv + e;
    const float* wk = Wk + h * Dv * Dv + e;
    const float* wv = Wv + h * Dv * Dv + e;

    float q = 0.f, k = 0.f, v = 0.f;
#pragma unroll
    for (int d = 0; d < Dv; ++d) {
        const float xv = xh[d];
        q = fmaf(xv, wq[d * Dv], q);
        k = fmaf(xv, wk[d * Dv], k);
        v = fmaf(xv, wv[d * Dv], v);
    }
    const int b_ = token >> 11, n_ = token & (Nv - 1);
    const size_t o = (((size_t)b_ * Hv + h) * Nv + n_) * Dv + e;
    Qb[o] = f2bf((q + bq[h * Dv + e]) * 0.125f);
    Kb[o] = f2bf(k + bk[h * Dv + e]);
    Vb[o] = f2bf(v + bv[h * Dv + e]);
}

// ---------------------------------------------------------------------------
// Kernel 2: V transpose per (b,h): [n][d] -> Vt [d][n]. 64x64 tiles through
// rotate-swizzled LDS (elem (n,d) at n*64 + ((d+n)&63)): conflict-free both ways.
// ---------------------------------------------------------------------------
__global__ __launch_bounds__(256) void vtrans_kernel(
    const unsigned short* __restrict__ Vb, unsigned short* __restrict__ Vt)
{
    const int bh = blockIdx.x >> 5;
    const int n0 = (blockIdx.x & 31) * 64;
    const int t = threadIdx.x;
    __shared__ unsigned short tile[64 * 64];

#pragma unroll
    for (int s0 = 0; s0 < 2; ++s0) {
        const int s = t + s0 * 256;
        const int r = s >> 3, c = s & 7;       // n-row, d-chunk
        const short8 v = *(const short8*)(Vb + ((size_t)bh * Nv + n0 + r) * Dv + c * 8);
#pragma unroll
        for (int j = 0; j < 8; ++j)
            tile[r * 64 + ((c * 8 + j + r) & 63)] = ((const unsigned short*)&v)[j];
    }
    __syncthreads();
#pragma unroll
    for (int s0 = 0; s0 < 2; ++s0) {
        const int s = t + s0 * 256;
        const int d = s >> 3, c = s & 7;       // d-row, n-chunk
        unsigned uu[4];
#pragma unroll
        for (int p = 0; p < 4; ++p) {
            const int na = c * 8 + 2 * p, nb = na + 1;
            const unsigned lo = tile[na * 64 + ((d + na) & 63)];
            const unsigned hi = tile[nb * 64 + ((d + nb) & 63)];
            uu[p] = lo | (hi << 16);
        }
        uint4 ov; ov.x = uu[0]; ov.y = uu[1]; ov.z = uu[2]; ov.w = uu[3];
        *(uint4*)(Vt + ((size_t)bh * Dv + d) * Nv + n0 + c * 8) = ov;
    }
}

// ---------------------------------------------------------------------------
// Kernel 3: flash attention, bf16 MFMA 16x16x32.
// Block: 4 waves, 64 q-rows (wave w owns rows w*16..+15). KV tile = 64.
// K tile [kv][d] and V^T tile [d][kv] in LDS, XOR chunk swizzle (c ^= row&7).
// Online softmax in registers; P via per-wave padded LDS (stride 80 elems).
// O written as [b][n][h*64+d] fp32.
// ---------------------------------------------------------------------------
__global__ __launch_bounds__(256) void attn_kernel(
    const unsigned short* __restrict__ Qb, const unsigned short* __restrict__ Kb,
    const unsigned short* __restrict__ Vt, float* __restrict__ O)
{
    const int qt = blockIdx.x & 31;
    const int bh = blockIdx.x >> 5;
    const int t = threadIdx.x, l = t & 63, w = t >> 6;
    const int lg = l >> 4, lc = l & 15;

    __shared__ uint4 Ks[64 * 8];               // 8 KB, [kv][chunk^]
    __shared__ uint4 Vs[64 * 8];               // 8 KB, [d][chunk^]
    __shared__ unsigned short Pl[4][16 * 80];  // 10 KB, per-wave P

    // Q fragments (A-operand): row = lc, k = kk*32 + lg*8 + j
    const unsigned short* Qg = Qb + (((size_t)bh * Nv) + qt * 64 + w * 16) * Dv;
    bf16x8 aq[2];
#pragma unroll
    for (int kk = 0; kk < 2; ++kk)
        aq[kk] = *(const bf16x8*)(Qg + (size_t)lc * Dv + kk * 32 + lg * 8);

    const unsigned short* Kg = Kb + (size_t)bh * Nv * Dv;
    const unsigned short* Vg = Vt + (size_t)bh * Dv * Nv;

    float m_run[4], l_run[4];
#pragma unroll
    for (int j = 0; j < 4; ++j) { m_run[j] = -1e30f; l_run[j] = 0.f; }
    f32x4 o_[4];
#pragma unroll
    for (int dt = 0; dt < 4; ++dt) o_[dt] = (f32x4){0.f, 0.f, 0.f, 0.f};

    for (int kt = 0; kt < Nv / 64; ++kt) {
        __syncthreads();
        // stage K tile rows kv=0..63 and V^T tile rows d=0..63 (8 chunks each)
#pragma unroll
        for (int s0 = 0; s0 < 2; ++s0) {
            const int s = t + s0 * 256;
            const int r = s >> 3, c = s & 7;
            const uint4 kreg = *(const uint4*)(Kg + ((size_t)(kt * 64 + r)) * Dv + c * 8);
            const uint4 vreg = *(const uint4*)(Vg + (size_t)r * Nv + kt * 64 + c * 8);
            Ks[r * 8 + (c ^ (r & 7))] = kreg;
            Vs[r * 8 + (c ^ (r & 7))] = vreg;
        }
        __syncthreads();

        // S = Q K^T : D[q=lg*4+j][kv=nt*16+lc]
        f32x4 s4[4];
#pragma unroll
        for (int nt = 0; nt < 4; ++nt) s4[nt] = (f32x4){0.f, 0.f, 0.f, 0.f};
#pragma unroll
        for (int kk = 0; kk < 2; ++kk) {
#pragma unroll
            for (int nt = 0; nt < 4; ++nt) {
                const int row = nt * 16 + lc;
                const bf16x8 b = ((const bf16x8*)Ks)[row * 8 + ((kk * 4 + lg) ^ (row & 7))];
                s4[nt] = __builtin_amdgcn_mfma_f32_16x16x32_bf16(aq[kk], b, s4[nt], 0, 0, 0);
            }
        }

        // online softmax (row = lg*4+j; reduce over nt in-lane, then 16 lanes)
        float tm[4];
#pragma unroll
        for (int j = 0; j < 4; ++j)
            tm[j] = fmaxf(fmaxf(s4[0][j], s4[1][j]), fmaxf(s4[2][j], s4[3][j]));
#pragma unroll
        for (int off = 1; off < 16; off <<= 1) {
#pragma unroll
            for (int j = 0; j < 4; ++j) tm[j] = fmaxf(tm[j], __shfl_xor(tm[j], off, 64));
        }
        float sc[4];
#pragma unroll
        for (int j = 0; j < 4; ++j) {
            const float mn = fmaxf(m_run[j], tm[j]);
            sc[j] = __expf(m_run[j] - mn);
            m_run[j] = mn;
        }
        float rs[4] = {0.f, 0.f, 0.f, 0.f};
#pragma unroll
        for (int nt = 0; nt < 4; ++nt) {
#pragma unroll
            for (int j = 0; j < 4; ++j) {
                const float p = __expf(s4[nt][j] - m_run[j]);
                rs[j] += p;
                Pl[w][(lg * 4 + j) * 80 + nt * 16 + lc] = f2bf(p);
            }
        }
#pragma unroll
        for (int off = 1; off < 16; off <<= 1) {
#pragma unroll
            for (int j = 0; j < 4; ++j) rs[j] += __shfl_xor(rs[j], off, 64);
        }
#pragma unroll
        for (int j = 0; j < 4; ++j) l_run[j] = l_run[j] * sc[j] + rs[j];
#pragma unroll
        for (int dt = 0; dt < 4; ++dt) {
#pragma unroll
            for (int j = 0; j < 4; ++j) o_[dt][j] *= sc[j];
        }

        // O += P V : A = P (row=lc, k=kv), B = V^T-tile rows d
#pragma unroll
        for (int ks = 0; ks < 2; ++ks) {
            const bf16x8 a = *(const bf16x8*)(&Pl[w][lc * 80 + ks * 32 + lg * 8]);
#pragma unroll
            for (int dt = 0; dt < 4; ++dt) {
                const int row = dt * 16 + lc;
                const bf16x8 b = ((const bf16x8*)Vs)[row * 8 + ((ks * 4 + lg) ^ (row & 7))];
                o_[dt] = __builtin_amdgcn_mfma_f32_16x16x32_bf16(a, b, o_[dt], 0, 0, 0);
            }
        }
    }

    // epilogue: O[b][n][h*64+d] = o/l
    const int b_ = bh >> 2, h_ = bh & 3;
#pragma unroll
    for (int j = 0; j < 4; ++j) {
        const float inv = 1.0f / l_run[j];
        const int qrow = qt * 64 + w * 16 + lg * 4 + j;
        float* orow = O + ((size_t)b_ * Nv + qrow) * HD + h_ * Dv;
#pragma unroll
        for (int dt = 0; dt < 4; ++dt) orow[dt * 16 + lc] = o_[dt][j] * inv;
    }
}

// ---------------------------------------------------------------------------
// Kernel 4: output projection. 8 tokens/block, register-blocked over Wp.
// ---------------------------------------------------------------------------
__global__ __launch_bounds__(256) void proj_kernel(
    const float* __restrict__ O, const float* __restrict__ Wp,
    const float* __restrict__ bp, float* __restrict__ out)
{
    const int base = blockIdx.x * 8;
    const int t = threadIdx.x;
    __shared__ float os[8 * OUTv];
#pragma unroll
    for (int i = 0; i < 8; ++i) os[i * OUTv + t] = O[(size_t)(base + i) * OUTv + t];
    __syncthreads();

    float acc[8];
    const float bias = bp[t];
#pragma unroll
    for (int i = 0; i < 8; ++i) acc[i] = bias;

    for (int c = 0; c < HD; ++c) {
        const float wv = Wp[(size_t)c * OUTv + t];
#pragma unroll
        for (int i = 0; i < 8; ++i) acc[i] = fmaf(os[i * OUTv + c], wv, acc[i]);
    }
#pragma unroll
    for (int i = 0; i < 8; ++i) out[(size_t)(base + i) * OUTv + t] = acc[i];
}

// ---------------------------------------------------------------------------
extern "C" void kernel_launch(void* const* d_in, const int* in_sizes, int n_in,
                              void* d_out, int out_size, void* d_ws, size_t ws_size,
                              hipStream_t stream)
{
    const float* x  = (const float*)d_in[0];
    const float* Wq = (const float*)d_in[1];
    const float* Wk = (const float*)d_in[2];
    const float* Wv = (const float*)d_in[3];
    const float* bq = (const float*)d_in[4];
    const float* bk = (const float*)d_in[5];
    const float* bv = (const float*)d_in[6];
    const float* Wp = (const float*)d_in[7];
    const float* bp = (const float*)d_in[8];
    float* out = (float*)d_out;

    unsigned short* us = (unsigned short*)d_ws;
    unsigned short* Qb = us;
    unsigned short* Kb = us + PH;
    unsigned short* Vb = us + 2 * PH;
    unsigned short* Vt = us + 3 * PH;
    float* O = (float*)(us + 4 * PH);           // 16 MB fp32, total ws use 48 MB

    qkv_kernel<<<Bv * Nv, 256, 0, stream>>>(x, Wq, Wk, Wv, bq, bk, bv, Qb, Kb, Vb);
    vtrans_kernel<<<BH * 32, 256, 0, stream>>>(Vb, Vt);
    attn_kernel<<<BH * 32, 256, 0, stream>>>(Qb, Kb, Vt, O);
    proj_kernel<<<(Bv * Nv) / 8, 256, 0, stream>>>(O, Wp, bp, out);
}

// Round 3
// 250.765 us; speedup vs baseline: 29.2802x; 1.6339x over previous
//
#include <hip/hip_runtime.h>

typedef __attribute__((ext_vector_type(4))) float f32x4;
typedef __attribute__((ext_vector_type(8))) __bf16 bf16x8;

constexpr int Bv = 8, Nv = 2048, Hv = 4, Dv = 64, OUTv = 256, HD = 256;
constexpr int BH = Bv * Hv;                      // 32
constexpr size_t PH = (size_t)BH * Nv * Dv;      // 4,194,304 bf16 elements per buffer

// round-to-nearest-even fp32 -> bf16 bits
__device__ __forceinline__ unsigned short f2bf(float f) {
    unsigned u = __float_as_uint(f);
    u += 0x7FFFu + ((u >> 16) & 1u);
    return (unsigned short)(u >> 16);
}

__device__ __forceinline__ uint4 pack8(const float* f) {
    uint4 u;
    u.x = (unsigned)f2bf(f[0]) | ((unsigned)f2bf(f[1]) << 16);
    u.y = (unsigned)f2bf(f[2]) | ((unsigned)f2bf(f[3]) << 16);
    u.z = (unsigned)f2bf(f[4]) | ((unsigned)f2bf(f[5]) << 16);
    u.w = (unsigned)f2bf(f[6]) | ((unsigned)f2bf(f[7]) << 16);
    return u;
}

// ---------------------------------------------------------------------------
// Kernel 1: QKV projection as MFMA GEMM. One block = (head h, 64-token tile).
// Stage x[64 tok][64 d] and Wt[64 e][64 d] (x3) as bf16 in LDS, XOR-chunk
// swizzle (chunk ^= row&7). 24 MFMAs/wave (16x16x32 bf16). Epilogue repacks
// through LDS: Q,K -> [bh][n][d]; V -> transposed [bh][d][n] (kills vtrans).
// Q pre-scaled by 1/sqrt(64) after bias.
// ---------------------------------------------------------------------------
__global__ __launch_bounds__(256) void qkv_kernel(
    const float* __restrict__ x,
    const float* __restrict__ Wq, const float* __restrict__ Wk, const float* __restrict__ Wv,
    const float* __restrict__ bq, const float* __restrict__ bk, const float* __restrict__ bv,
    unsigned short* __restrict__ Qb, unsigned short* __restrict__ Kb,
    unsigned short* __restrict__ Vt)
{
    const int h = blockIdx.x & 3;
    const int tt = blockIdx.x >> 2;          // token tile [0, 256)
    const int tok0 = tt * 64;                // global token base (b*2048+n), tile within one b
    const int t = threadIdx.x, l = t & 63, w = t >> 6;
    const int lg = l >> 4, lc = l & 15;

    __shared__ uint4 Xs[64 * 8];             // 8 KB  [tok][d-chunk^]
    __shared__ uint4 Ws[3][64 * 8];          // 24 KB [e][d-chunk^] (W transposed)
    __shared__ uint4 Os[64 * 8];             // 8 KB  repack buffer

    // ---- stage x tile -> bf16 (thread: row r = t>>2, 16 floats at (t&3)*16)
    {
        const int r = t >> 2, c4 = t & 3;
        const float* src = x + (size_t)(tok0 + r) * HD + h * Dv + c4 * 16;
        float f[16];
        *(float4*)(f)      = *(const float4*)(src);
        *(float4*)(f + 4)  = *(const float4*)(src + 4);
        *(float4*)(f + 8)  = *(const float4*)(src + 8);
        *(float4*)(f + 12) = *(const float4*)(src + 12);
        Xs[r * 8 + ((c4 * 2)     ^ (r & 7))] = pack8(f);
        Xs[r * 8 + ((c4 * 2 + 1) ^ (r & 7))] = pack8(f + 8);
    }
    // ---- stage W^T (column loads), 3 matrices
    {
        const int e = t >> 2, c4 = t & 3;
        const float* wsrcs[3] = {Wq + h * Dv * Dv + e, Wk + h * Dv * Dv + e, Wv + h * Dv * Dv + e};
#pragma unroll
        for (int m = 0; m < 3; ++m) {
            float f[16];
#pragma unroll
            for (int dd = 0; dd < 16; ++dd) f[dd] = wsrcs[m][(c4 * 16 + dd) * Dv];
            Ws[m][e * 8 + ((c4 * 2)     ^ (e & 7))] = pack8(f);
            Ws[m][e * 8 + ((c4 * 2 + 1) ^ (e & 7))] = pack8(f + 8);
        }
    }
    __syncthreads();

    // ---- MFMA: C[tok][e] = X @ W (A row = w*16+lc, k-chunks; B n = nt*16+lc)
    const int ar = w * 16 + lc;
    bf16x8 a[2];
    a[0] = ((const bf16x8*)Xs)[ar * 8 + (lg       ^ (ar & 7))];
    a[1] = ((const bf16x8*)Xs)[ar * 8 + ((4 + lg) ^ (ar & 7))];

    f32x4 acc[3][4];
#pragma unroll
    for (int m = 0; m < 3; ++m)
#pragma unroll
        for (int nt = 0; nt < 4; ++nt) acc[m][nt] = (f32x4){0.f, 0.f, 0.f, 0.f};

#pragma unroll
    for (int kk = 0; kk < 2; ++kk) {
#pragma unroll
        for (int m = 0; m < 3; ++m) {
#pragma unroll
            for (int nt = 0; nt < 4; ++nt) {
                const int br = nt * 16 + lc;
                const bf16x8 b = ((const bf16x8*)Ws[m])[br * 8 + ((kk * 4 + lg) ^ (br & 7))];
                acc[m][nt] = __builtin_amdgcn_mfma_f32_16x16x32_bf16(a[kk], b, acc[m][nt], 0, 0, 0);
            }
        }
    }

    // ---- epilogue: bias (+scale for Q), repack via LDS, coalesced stores
    const int b_ = tok0 >> 11, n_ = tok0 & (Nv - 1);
    const int bh = b_ * Hv + h;
    unsigned short* Os16 = (unsigned short*)Os;
    const float* biases[3] = {bq + h * Dv, bk + h * Dv, bv + h * Dv};

#pragma unroll
    for (int m = 0; m < 3; ++m) {
        if (m) __syncthreads();
        if (m < 2) {
            // layout [tok][e]
#pragma unroll
            for (int nt = 0; nt < 4; ++nt) {
                const int e = nt * 16 + lc;
                const float bias = biases[m][e];
#pragma unroll
                for (int j = 0; j < 4; ++j) {
                    float v = acc[m][nt][j] + bias;
                    if (m == 0) v *= 0.125f;
                    const int row = w * 16 + lg * 4 + j;
                    const int ch = (e >> 3) ^ (row & 7);
                    Os16[row * 64 + ch * 8 + (e & 7)] = f2bf(v);
                }
            }
            __syncthreads();
            const int r = t >> 2, c4 = t & 3;
            unsigned short* dst = (m == 0 ? Qb : Kb) + ((size_t)bh * Nv + n_ + r) * Dv + c4 * 16;
            *(uint4*)dst       = Os[r * 8 + ((c4 * 2)     ^ (r & 7))];
            *(uint4*)(dst + 8) = Os[r * 8 + ((c4 * 2 + 1) ^ (r & 7))];
        } else {
            // V transposed: layout [e][tok]
#pragma unroll
            for (int nt = 0; nt < 4; ++nt) {
                const int e = nt * 16 + lc;
                const float bias = biases[2][e];
#pragma unroll
                for (int j = 0; j < 4; ++j) {
                    const int tok = w * 16 + lg * 4 + j;
                    const int ch = (tok >> 3) ^ (e & 7);
                    Os16[e * 64 + ch * 8 + (tok & 7)] = f2bf(acc[2][nt][j] + bias);
                }
            }
            __syncthreads();
            const int e = t >> 2, c4 = t & 3;
            unsigned short* dst = Vt + ((size_t)bh * Dv + e) * Nv + n_ + c4 * 16;
            *(uint4*)dst       = Os[e * 8 + ((c4 * 2)     ^ (e & 7))];
            *(uint4*)(dst + 8) = Os[e * 8 + ((c4 * 2 + 1) ^ (e & 7))];
        }
    }
}

// ---------------------------------------------------------------------------
// Kernel 2: flash attention, bf16 MFMA 16x16x32. (unchanged from round 1)
// ---------------------------------------------------------------------------
__global__ __launch_bounds__(256) void attn_kernel(
    const unsigned short* __restrict__ Qb, const unsigned short* __restrict__ Kb,
    const unsigned short* __restrict__ Vt, float* __restrict__ O)
{
    const int qt = blockIdx.x & 31;
    const int bh = blockIdx.x >> 5;
    const int t = threadIdx.x, l = t & 63, w = t >> 6;
    const int lg = l >> 4, lc = l & 15;

    __shared__ uint4 Ks[64 * 8];               // 8 KB, [kv][chunk^]
    __shared__ uint4 Vs[64 * 8];               // 8 KB, [d][chunk^]
    __shared__ unsigned short Pl[4][16 * 80];  // 10 KB, per-wave P

    const unsigned short* Qg = Qb + (((size_t)bh * Nv) + qt * 64 + w * 16) * Dv;
    bf16x8 aq[2];
#pragma unroll
    for (int kk = 0; kk < 2; ++kk)
        aq[kk] = *(const bf16x8*)(Qg + (size_t)lc * Dv + kk * 32 + lg * 8);

    const unsigned short* Kg = Kb + (size_t)bh * Nv * Dv;
    const unsigned short* Vg = Vt + (size_t)bh * Dv * Nv;

    float m_run[4], l_run[4];
#pragma unroll
    for (int j = 0; j < 4; ++j) { m_run[j] = -1e30f; l_run[j] = 0.f; }
    f32x4 o_[4];
#pragma unroll
    for (int dt = 0; dt < 4; ++dt) o_[dt] = (f32x4){0.f, 0.f, 0.f, 0.f};

    for (int kt = 0; kt < Nv / 64; ++kt) {
        __syncthreads();
#pragma unroll
        for (int s0 = 0; s0 < 2; ++s0) {
            const int s = t + s0 * 256;
            const int r = s >> 3, c = s & 7;
            const uint4 kreg = *(const uint4*)(Kg + ((size_t)(kt * 64 + r)) * Dv + c * 8);
            const uint4 vreg = *(const uint4*)(Vg + (size_t)r * Nv + kt * 64 + c * 8);
            Ks[r * 8 + (c ^ (r & 7))] = kreg;
            Vs[r * 8 + (c ^ (r & 7))] = vreg;
        }
        __syncthreads();

        f32x4 s4[4];
#pragma unroll
        for (int nt = 0; nt < 4; ++nt) s4[nt] = (f32x4){0.f, 0.f, 0.f, 0.f};
#pragma unroll
        for (int kk = 0; kk < 2; ++kk) {
#pragma unroll
            for (int nt = 0; nt < 4; ++nt) {
                const int row = nt * 16 + lc;
                const bf16x8 b = ((const bf16x8*)Ks)[row * 8 + ((kk * 4 + lg) ^ (row & 7))];
                s4[nt] = __builtin_amdgcn_mfma_f32_16x16x32_bf16(aq[kk], b, s4[nt], 0, 0, 0);
            }
        }

        float tm[4];
#pragma unroll
        for (int j = 0; j < 4; ++j)
            tm[j] = fmaxf(fmaxf(s4[0][j], s4[1][j]), fmaxf(s4[2][j], s4[3][j]));
#pragma unroll
        for (int off = 1; off < 16; off <<= 1) {
#pragma unroll
            for (int j = 0; j < 4; ++j) tm[j] = fmaxf(tm[j], __shfl_xor(tm[j], off, 64));
        }
        float sc[4];
#pragma unroll
        for (int j = 0; j < 4; ++j) {
            const float mn = fmaxf(m_run[j], tm[j]);
            sc[j] = __expf(m_run[j] - mn);
            m_run[j] = mn;
        }
        float rs[4] = {0.f, 0.f, 0.f, 0.f};
#pragma unroll
        for (int nt = 0; nt < 4; ++nt) {
#pragma unroll
            for (int j = 0; j < 4; ++j) {
                const float p = __expf(s4[nt][j] - m_run[j]);
                rs[j] += p;
                Pl[w][(lg * 4 + j) * 80 + nt * 16 + lc] = f2bf(p);
            }
        }
#pragma unroll
        for (int off = 1; off < 16; off <<= 1) {
#pragma unroll
            for (int j = 0; j < 4; ++j) rs[j] += __shfl_xor(rs[j], off, 64);
        }
#pragma unroll
        for (int j = 0; j < 4; ++j) l_run[j] = l_run[j] * sc[j] + rs[j];
#pragma unroll
        for (int dt = 0; dt < 4; ++dt) {
#pragma unroll
            for (int j = 0; j < 4; ++j) o_[dt][j] *= sc[j];
        }

#pragma unroll
        for (int ks = 0; ks < 2; ++ks) {
            const bf16x8 a = *(const bf16x8*)(&Pl[w][lc * 80 + ks * 32 + lg * 8]);
#pragma unroll
            for (int dt = 0; dt < 4; ++dt) {
                const int row = dt * 16 + lc;
                const bf16x8 b = ((const bf16x8*)Vs)[row * 8 + ((ks * 4 + lg) ^ (row & 7))];
                o_[dt] = __builtin_amdgcn_mfma_f32_16x16x32_bf16(a, b, o_[dt], 0, 0, 0);
            }
        }
    }

    const int b_ = bh >> 2, h_ = bh & 3;
#pragma unroll
    for (int j = 0; j < 4; ++j) {
        const float inv = 1.0f / l_run[j];
        const int qrow = qt * 64 + w * 16 + lg * 4 + j;
        float* orow = O + ((size_t)b_ * Nv + qrow) * HD + h_ * Dv;
#pragma unroll
        for (int dt = 0; dt < 4; ++dt) orow[dt * 16 + lc] = o_[dt][j] * inv;
    }
}

// ---------------------------------------------------------------------------
// Kernel 3: output projection. 8 tokens/block, register-blocked over Wp.
// ---------------------------------------------------------------------------
__global__ __launch_bounds__(256) void proj_kernel(
    const float* __restrict__ O, const float* __restrict__ Wp,
    const float* __restrict__ bp, float* __restrict__ out)
{
    const int base = blockIdx.x * 8;
    const int t = threadIdx.x;
    __shared__ float os[8 * OUTv];
#pragma unroll
    for (int i = 0; i < 8; ++i) os[i * OUTv + t] = O[(size_t)(base + i) * OUTv + t];
    __syncthreads();

    float acc[8];
    const float bias = bp[t];
#pragma unroll
    for (int i = 0; i < 8; ++i) acc[i] = bias;

    for (int c = 0; c < HD; ++c) {
        const float wv = Wp[(size_t)c * OUTv + t];
#pragma unroll
        for (int i = 0; i < 8; ++i) acc[i] = fmaf(os[i * OUTv + c], wv, acc[i]);
    }
#pragma unroll
    for (int i = 0; i < 8; ++i) out[(size_t)(base + i) * OUTv + t] = acc[i];
}

// ---------------------------------------------------------------------------
extern "C" void kernel_launch(void* const* d_in, const int* in_sizes, int n_in,
                              void* d_out, int out_size, void* d_ws, size_t ws_size,
                              hipStream_t stream)
{
    const float* x  = (const float*)d_in[0];
    const float* Wq = (const float*)d_in[1];
    const float* Wk = (const float*)d_in[2];
    const float* Wv = (const float*)d_in[3];
    const float* bq = (const float*)d_in[4];
    const float* bk = (const float*)d_in[5];
    const float* bv = (const float*)d_in[6];
    const float* Wp = (const float*)d_in[7];
    const float* bp = (const float*)d_in[8];
    float* out = (float*)d_out;

    unsigned short* us = (unsigned short*)d_ws;
    unsigned short* Qb = us;
    unsigned short* Kb = us + PH;
    unsigned short* Vt = us + 2 * PH;
    float* O = (float*)(us + 3 * PH);           // 16 MB fp32; total ws use 40 MB

    qkv_kernel<<<(Bv * Nv / 64) * Hv, 256, 0, stream>>>(x, Wq, Wk, Wv, bq, bk, bv, Qb, Kb, Vt);
    attn_kernel<<<BH * 32, 256, 0, stream>>>(Qb, Kb, Vt, O);
    proj_kernel<<<(Bv * Nv) / 8, 256, 0, stream>>>(O, Wp, bp, out);
}

// Round 4
// 194.518 us; speedup vs baseline: 37.7469x; 1.2892x over previous
//
#include <hip/hip_runtime.h>

typedef __attribute__((ext_vector_type(4)))  float  f32x4;
typedef __attribute__((ext_vector_type(16))) float  f32x16;
typedef __attribute__((ext_vector_type(8)))  __bf16 bf16x8;
typedef __attribute__((ext_vector_type(2)))  unsigned u32x2;

constexpr int Bv = 8, Nv = 2048, Hv = 4, Dv = 64, OUTv = 256, HD = 256;
constexpr int BH = Bv * Hv;                      // 32
constexpr size_t PH = (size_t)BH * Nv * Dv;      // bf16 elements per buffer

#if __has_builtin(__builtin_amdgcn_exp2f)
#define EXP2(x) __builtin_amdgcn_exp2f(x)
#else
#define EXP2(x) exp2f(x)
#endif

// round-to-nearest-even fp32 -> bf16 bits
__device__ __forceinline__ unsigned short f2bf(float f) {
    unsigned u = __float_as_uint(f);
    u += 0x7FFFu + ((u >> 16) & 1u);
    return (unsigned short)(u >> 16);
}

__device__ __forceinline__ uint4 pack8(const float* f) {
    uint4 u;
    u.x = (unsigned)f2bf(f[0]) | ((unsigned)f2bf(f[1]) << 16);
    u.y = (unsigned)f2bf(f[2]) | ((unsigned)f2bf(f[3]) << 16);
    u.z = (unsigned)f2bf(f[4]) | ((unsigned)f2bf(f[5]) << 16);
    u.w = (unsigned)f2bf(f[6]) | ((unsigned)f2bf(f[7]) << 16);
    return u;
}

// pack two f32 -> one dword of 2 bf16 (compiler fuses to v_cvt_pk_bf16_f32)
__device__ __forceinline__ unsigned pk_bf16(float a, float b) {
    unsigned short x = f2bf(a), y = f2bf(b);
    return (unsigned)x | ((unsigned)y << 16);
}

// permlane32_swap(a,b) -> {lo, hi}:
//   lo: hi0 lanes get own a, hi1 lanes get partner(hi0)'s b
//   hi: hi0 lanes get partner(hi1)'s a, hi1 lanes get own b
__device__ __forceinline__ void swap32(unsigned a, unsigned b, unsigned& lo, unsigned& hi) {
#if __has_builtin(__builtin_amdgcn_permlane32_swap)
    u32x2 r = __builtin_amdgcn_permlane32_swap(a, b, false, false);
    lo = r.x; hi = r.y;
#else
    const int ishi = (threadIdx.x & 63) >> 5;
    unsigned pa = __shfl_xor(a, 32, 64), pb = __shfl_xor(b, 32, 64);
    lo = ishi ? pb : a;
    hi = ishi ? b : pa;
#endif
}

// ---------------------------------------------------------------------------
// Kernel 1: QKV projection as MFMA GEMM (unchanged except Q scale now folds
// log2(e) so attention works in exp2 domain). Q,K -> [bh][n][d]; V -> [bh][d][n].
// ---------------------------------------------------------------------------
__global__ __launch_bounds__(256) void qkv_kernel(
    const float* __restrict__ x,
    const float* __restrict__ Wq, const float* __restrict__ Wk, const float* __restrict__ Wv,
    const float* __restrict__ bq, const float* __restrict__ bk, const float* __restrict__ bv,
    unsigned short* __restrict__ Qb, unsigned short* __restrict__ Kb,
    unsigned short* __restrict__ Vt)
{
    const int h = blockIdx.x & 3;
    const int tt = blockIdx.x >> 2;
    const int tok0 = tt * 64;
    const int t = threadIdx.x, l = t & 63, w = t >> 6;
    const int lg = l >> 4, lc = l & 15;

    __shared__ uint4 Xs[64 * 8];
    __shared__ uint4 Ws[3][64 * 8];
    __shared__ uint4 Os[64 * 8];

    {
        const int r = t >> 2, c4 = t & 3;
        const float* src = x + (size_t)(tok0 + r) * HD + h * Dv + c4 * 16;
        float f[16];
        *(float4*)(f)      = *(const float4*)(src);
        *(float4*)(f + 4)  = *(const float4*)(src + 4);
        *(float4*)(f + 8)  = *(const float4*)(src + 8);
        *(float4*)(f + 12) = *(const float4*)(src + 12);
        Xs[r * 8 + ((c4 * 2)     ^ (r & 7))] = pack8(f);
        Xs[r * 8 + ((c4 * 2 + 1) ^ (r & 7))] = pack8(f + 8);
    }
    {
        const int e = t >> 2, c4 = t & 3;
        const float* wsrcs[3] = {Wq + h * Dv * Dv + e, Wk + h * Dv * Dv + e, Wv + h * Dv * Dv + e};
#pragma unroll
        for (int m = 0; m < 3; ++m) {
            float f[16];
#pragma unroll
            for (int dd = 0; dd < 16; ++dd) f[dd] = wsrcs[m][(c4 * 16 + dd) * Dv];
            Ws[m][e * 8 + ((c4 * 2)     ^ (e & 7))] = pack8(f);
            Ws[m][e * 8 + ((c4 * 2 + 1) ^ (e & 7))] = pack8(f + 8);
        }
    }
    __syncthreads();

    const int ar = w * 16 + lc;
    bf16x8 a[2];
    a[0] = ((const bf16x8*)Xs)[ar * 8 + (lg       ^ (ar & 7))];
    a[1] = ((const bf16x8*)Xs)[ar * 8 + ((4 + lg) ^ (ar & 7))];

    f32x4 acc[3][4];
#pragma unroll
    for (int m = 0; m < 3; ++m)
#pragma unroll
        for (int nt = 0; nt < 4; ++nt) acc[m][nt] = (f32x4){0.f, 0.f, 0.f, 0.f};

#pragma unroll
    for (int kk = 0; kk < 2; ++kk) {
#pragma unroll
        for (int m = 0; m < 3; ++m) {
#pragma unroll
            for (int nt = 0; nt < 4; ++nt) {
                const int br = nt * 16 + lc;
                const bf16x8 b = ((const bf16x8*)Ws[m])[br * 8 + ((kk * 4 + lg) ^ (br & 7))];
                acc[m][nt] = __builtin_amdgcn_mfma_f32_16x16x32_bf16(a[kk], b, acc[m][nt], 0, 0, 0);
            }
        }
    }

    const int b_ = tok0 >> 11, n_ = tok0 & (Nv - 1);
    const int bh = b_ * Hv + h;
    unsigned short* Os16 = (unsigned short*)Os;
    const float* biases[3] = {bq + h * Dv, bk + h * Dv, bv + h * Dv};
    const float QSCALE = 0.125f * 1.44269504088896340736f;  // 1/sqrt(64) * log2(e)

#pragma unroll
    for (int m = 0; m < 3; ++m) {
        if (m) __syncthreads();
        if (m < 2) {
#pragma unroll
            for (int nt = 0; nt < 4; ++nt) {
                const int e = nt * 16 + lc;
                const float bias = biases[m][e];
#pragma unroll
                for (int j = 0; j < 4; ++j) {
                    float v = acc[m][nt][j] + bias;
                    if (m == 0) v *= QSCALE;
                    const int row = w * 16 + lg * 4 + j;
                    const int ch = (e >> 3) ^ (row & 7);
                    Os16[row * 64 + ch * 8 + (e & 7)] = f2bf(v);
                }
            }
            __syncthreads();
            const int r = t >> 2, c4 = t & 3;
            unsigned short* dst = (m == 0 ? Qb : Kb) + ((size_t)bh * Nv + n_ + r) * Dv + c4 * 16;
            *(uint4*)dst       = Os[r * 8 + ((c4 * 2)     ^ (r & 7))];
            *(uint4*)(dst + 8) = Os[r * 8 + ((c4 * 2 + 1) ^ (r & 7))];
        } else {
#pragma unroll
            for (int nt = 0; nt < 4; ++nt) {
                const int e = nt * 16 + lc;
                const float bias = biases[2][e];
#pragma unroll
                for (int j = 0; j < 4; ++j) {
                    const int tok = w * 16 + lg * 4 + j;
                    const int ch = (tok >> 3) ^ (e & 7);
                    Os16[e * 64 + ch * 8 + (tok & 7)] = f2bf(acc[2][nt][j] + bias);
                }
            }
            __syncthreads();
            const int e = t >> 2, c4 = t & 3;
            unsigned short* dst = Vt + ((size_t)bh * Dv + e) * Nv + n_ + c4 * 16;
            *(uint4*)dst       = Os[e * 8 + ((c4 * 2)     ^ (e & 7))];
            *(uint4*)(dst + 8) = Os[e * 8 + ((c4 * 2 + 1) ^ (e & 7))];
        }
    }
}

// ---------------------------------------------------------------------------
// Kernel 2: flash attention, 32x32x16 MFMA, swapped-QK^T (S^T), in-register
// P redistribution via permlane32_swap, O^T accumulation (stats lane-local),
// KV tile 128 double-buffered via global_load_lds (width 16, pre-swizzled src).
// Block: 4 waves x 32 q-rows = 128 q. Grid bid = qt*32 + bh (bh%8 -> XCD).
// ---------------------------------------------------------------------------
__global__ __launch_bounds__(256, 2) void attn_kernel(
    const unsigned short* __restrict__ Qb, const unsigned short* __restrict__ Kb,
    const unsigned short* __restrict__ Vt, float* __restrict__ O)
{
    const int bh = blockIdx.x & 31;
    const int qt = blockIdx.x >> 5;
    const int t = threadIdx.x, w = t >> 6, l = t & 63;
    const int hi = l >> 5, lc = l & 31;

    __shared__ uint4 Ks[2][128 * 8];   // [kv][d-chunk^], 16KB each
    __shared__ uint4 Vs[2][64 * 16];   // [d][kv-chunk^], 16KB each

    const unsigned short* Kg = Kb + (size_t)bh * Nv * Dv;
    const unsigned short* Vg = Vt + (size_t)bh * Dv * Nv;

    // Q fragments (B-operand): col=q=lc, k = kk*16 + hi*8 + j
    const int q_ = qt * 128 + w * 32 + lc;
    const unsigned short* Qrow = Qb + ((size_t)bh * Nv + q_) * Dv;
    bf16x8 qf[4];
#pragma unroll
    for (int kk = 0; kk < 4; ++kk)
        qf[kk] = *(const bf16x8*)(Qrow + kk * 16 + hi * 8);

    // stage one 128-KV tile into buffer buf (K 16KB + V 16KB), async
    auto stage = [&](int buf, int kt) {
#pragma unroll
        for (int k = 0; k < 4; ++k) {
            const int s = k * 256 + t;
            const int base = k * 256 + w * 64;     // wave-uniform LDS slot base
            {   // K tile: [128 rows][8 chunks], phys chunk = c ^ (r&7)
                const int r = s >> 3, c = (s & 7) ^ (r & 7);
                __builtin_amdgcn_global_load_lds(
                    (const __attribute__((address_space(1))) unsigned int*)(Kg + ((size_t)kt * 128 + r) * Dv + c * 8),
                    (__attribute__((address_space(3))) unsigned int*)((char*)&Ks[buf][0] + base * 16),
                    16, 0, 0);
            }
            {   // V tile: [64 rows][16 chunks], phys chunk = c ^ (r&15)
                const int r = s >> 4, c = (s & 15) ^ (r & 15);
                __builtin_amdgcn_global_load_lds(
                    (const __attribute__((address_space(1))) unsigned int*)(Vg + (size_t)r * Nv + kt * 128 + c * 8),
                    (__attribute__((address_space(3))) unsigned int*)((char*)&Vs[buf][0] + base * 16),
                    16, 0, 0);
            }
        }
    };

    f32x16 o0, o1;
#pragma unroll
    for (int i = 0; i < 16; ++i) { o0[i] = 0.f; o1[i] = 0.f; }
    float m_run = -1e30f, l_part = 0.f;

    stage(0, 0);
    asm volatile("s_waitcnt vmcnt(0)" ::: "memory");
    __syncthreads();

    int cur = 0;
    for (int kt = 0; kt < Nv / 128; ++kt) {
        if (kt < Nv / 128 - 1) stage(cur ^ 1, kt + 1);

        const uint4* KsB = &Ks[cur][0];
        const uint4* VsB = &Vs[cur][0];

        // ---- S^T = K Q^T : s4[nt] D[row=kv][col=q]
        f32x16 s4[4];
#pragma unroll
        for (int nt = 0; nt < 4; ++nt) {
#pragma unroll
            for (int i = 0; i < 16; ++i) s4[nt][i] = 0.f;
        }
#pragma unroll
        for (int kk = 0; kk < 4; ++kk) {
#pragma unroll
            for (int nt = 0; nt < 4; ++nt) {
                const int r = nt * 32 + lc;
                const bf16x8 af = *(const bf16x8*)&KsB[r * 8 + ((kk * 2 + hi) ^ (r & 7))];
                s4[nt] = __builtin_amdgcn_mfma_f32_32x32x16_bf16(af, qf[kk], s4[nt], 0, 0, 0);
            }
        }

        // ---- tile max (in-lane tree + one cross-half swap)
        float v16[16];
#pragma unroll
        for (int r = 0; r < 16; ++r)
            v16[r] = fmaxf(fmaxf(s4[0][r], s4[1][r]), fmaxf(s4[2][r], s4[3][r]));
#pragma unroll
        for (int st = 8; st; st >>= 1)
#pragma unroll
            for (int r = 0; r < st; ++r) v16[r] = fmaxf(v16[r], v16[r + st]);
        float tm = fmaxf(v16[0], __shfl_xor(v16[0], 32, 64));

        // ---- defer-max rescale (THR = 8 in log2 domain)
        if (!__all(tm <= m_run + 8.f)) {
            const float m_new = fmaxf(m_run, tm);
            const float sc = EXP2(m_run - m_new);
            m_run = m_new;
            l_part *= sc;
#pragma unroll
            for (int i = 0; i < 16; ++i) { o0[i] *= sc; o1[i] *= sc; }
        }

        // ---- P = exp2(S - m), sum, pack, permlane-redistribute, PV
        float tsa[4] = {0.f, 0.f, 0.f, 0.f};
#pragma unroll
        for (int nt = 0; nt < 4; ++nt) {
#pragma unroll
            for (int r = 0; r < 16; ++r) {
                const float p = EXP2(s4[nt][r] - m_run);
                s4[nt][r] = p;
                tsa[r & 3] += p;
            }
            unsigned c[8];
#pragma unroll
            for (int i = 0; i < 8; ++i) c[i] = pk_bf16(s4[nt][2 * i], s4[nt][2 * i + 1]);

            unsigned d0a, d2a, d1a, d3a, d0b, d2b, d1b, d3b;
            swap32(c[0], c[2], d0a, d2a);
            swap32(c[1], c[3], d1a, d3a);
            swap32(c[4], c[6], d0b, d2b);
            swap32(c[5], c[7], d1b, d3b);

            union { unsigned u[4]; bf16x8 v; } pf0, pf1;
            pf0.u[0] = d0a; pf0.u[1] = d1a; pf0.u[2] = d2a; pf0.u[3] = d3a;  // ks = nt*2
            pf1.u[0] = d0b; pf1.u[1] = d1b; pf1.u[2] = d2b; pf1.u[3] = d3b;  // ks = nt*2+1

#pragma unroll
            for (int kslow = 0; kslow < 2; ++kslow) {
                const bf16x8 pf = kslow ? pf1.v : pf0.v;
                {
                    const int row = lc;                 // dblk 0
                    const int ch = (nt * 4 + kslow * 2 + hi) ^ (row & 15);
                    const bf16x8 vf = *(const bf16x8*)&VsB[row * 16 + ch];
                    o0 = __builtin_amdgcn_mfma_f32_32x32x16_bf16(vf, pf, o0, 0, 0, 0);
                }
                {
                    const int row = 32 + lc;            // dblk 1
                    const int ch = (nt * 4 + kslow * 2 + hi) ^ (row & 15);
                    const bf16x8 vf = *(const bf16x8*)&VsB[row * 16 + ch];
                    o1 = __builtin_amdgcn_mfma_f32_32x32x16_bf16(vf, pf, o1, 0, 0, 0);
                }
            }
        }
        l_part += (tsa[0] + tsa[1]) + (tsa[2] + tsa[3]);

        if (kt < Nv / 128 - 1) {
            asm volatile("s_waitcnt vmcnt(0)" ::: "memory");
            __syncthreads();
            cur ^= 1;
        }
    }

    // ---- epilogue: O[b][n][h*64+d] = O^T / l   (d = (r&3) + 4*hi + 8*(r>>2) + 32*dblk)
    const float lf = l_part + __shfl_xor(l_part, 32, 64);
    const float inv = 1.0f / lf;
    const int b_ = bh >> 2, h_ = bh & 3;
    float* orow = O + ((size_t)b_ * Nv + q_) * HD + h_ * Dv;
#pragma unroll
    for (int g = 0; g < 4; ++g) {
        float4 va, vb;
        va.x = o0[g * 4 + 0] * inv; va.y = o0[g * 4 + 1] * inv;
        va.z = o0[g * 4 + 2] * inv; va.w = o0[g * 4 + 3] * inv;
        vb.x = o1[g * 4 + 0] * inv; vb.y = o1[g * 4 + 1] * inv;
        vb.z = o1[g * 4 + 2] * inv; vb.w = o1[g * 4 + 3] * inv;
        *(float4*)(orow + 8 * g + 4 * hi)      = va;
        *(float4*)(orow + 32 + 8 * g + 4 * hi) = vb;
    }
}

// ---------------------------------------------------------------------------
// Kernel 3: output projection. 8 tokens/block, register-blocked over Wp.
// ---------------------------------------------------------------------------
__global__ __launch_bounds__(256) void proj_kernel(
    const float* __restrict__ O, const float* __restrict__ Wp,
    const float* __restrict__ bp, float* __restrict__ out)
{
    const int base = blockIdx.x * 8;
    const int t = threadIdx.x;
    __shared__ float os[8 * OUTv];
#pragma unroll
    for (int i = 0; i < 8; ++i) os[i * OUTv + t] = O[(size_t)(base + i) * OUTv + t];
    __syncthreads();

    float acc[8];
    const float bias = bp[t];
#pragma unroll
    for (int i = 0; i < 8; ++i) acc[i] = bias;

    for (int c = 0; c < HD; ++c) {
        const float wv = Wp[(size_t)c * OUTv + t];
#pragma unroll
        for (int i = 0; i < 8; ++i) acc[i] = fmaf(os[i * OUTv + c], wv, acc[i]);
    }
#pragma unroll
    for (int i = 0; i < 8; ++i) out[(size_t)(base + i) * OUTv + t] = acc[i];
}

// ---------------------------------------------------------------------------
extern "C" void kernel_launch(void* const* d_in, const int* in_sizes, int n_in,
                              void* d_out, int out_size, void* d_ws, size_t ws_size,
                              hipStream_t stream)
{
    const float* x  = (const float*)d_in[0];
    const float* Wq = (const float*)d_in[1];
    const float* Wk = (const float*)d_in[2];
    const float* Wv = (const float*)d_in[3];
    const float* bq = (const float*)d_in[4];
    const float* bk = (const float*)d_in[5];
    const float* bv = (const float*)d_in[6];
    const float* Wp = (const float*)d_in[7];
    const float* bp = (const float*)d_in[8];
    float* out = (float*)d_out;

    unsigned short* us = (unsigned short*)d_ws;
    unsigned short* Qb = us;
    unsigned short* Kb = us + PH;
    unsigned short* Vt = us + 2 * PH;
    float* O = (float*)(us + 3 * PH);

    qkv_kernel<<<(Bv * Nv / 64) * Hv, 256, 0, stream>>>(x, Wq, Wk, Wv, bq, bk, bv, Qb, Kb, Vt);
    attn_kernel<<<(Nv / 128) * BH, 256, 0, stream>>>(Qb, Kb, Vt, O);
    proj_kernel<<<(Bv * Nv) / 8, 256, 0, stream>>>(O, Wp, bp, out);
}

// Round 5
// 155.966 us; speedup vs baseline: 47.0773x; 1.2472x over previous
//
#include <hip/hip_runtime.h>

typedef __attribute__((ext_vector_type(4)))  float  f32x4;
typedef __attribute__((ext_vector_type(16))) float  f32x16;
typedef __attribute__((ext_vector_type(8)))  __bf16 bf16x8;
typedef __attribute__((ext_vector_type(2)))  unsigned u32x2;

constexpr int Bv = 8, Nv = 2048, Hv = 4, Dv = 64, OUTv = 256, HD = 256;
constexpr int BH = Bv * Hv;                      // 32
constexpr size_t PH = (size_t)BH * Nv * Dv;      // elements per [bh][n][d] buffer

#if __has_builtin(__builtin_amdgcn_exp2f)
#define EXP2(x) __builtin_amdgcn_exp2f(x)
#else
#define EXP2(x) exp2f(x)
#endif

__device__ __forceinline__ unsigned short f2bf(float f) {
    unsigned u = __float_as_uint(f);
    u += 0x7FFFu + ((u >> 16) & 1u);
    return (unsigned short)(u >> 16);
}

__device__ __forceinline__ uint4 pack8(const float* f) {
    uint4 u;
    u.x = (unsigned)f2bf(f[0]) | ((unsigned)f2bf(f[1]) << 16);
    u.y = (unsigned)f2bf(f[2]) | ((unsigned)f2bf(f[3]) << 16);
    u.z = (unsigned)f2bf(f[4]) | ((unsigned)f2bf(f[5]) << 16);
    u.w = (unsigned)f2bf(f[6]) | ((unsigned)f2bf(f[7]) << 16);
    return u;
}

__device__ __forceinline__ unsigned pk_bf16(float a, float b) {
    unsigned short x = f2bf(a), y = f2bf(b);
    return (unsigned)x | ((unsigned)y << 16);
}

__device__ __forceinline__ void swap32(unsigned a, unsigned b, unsigned& lo, unsigned& hi) {
#if __has_builtin(__builtin_amdgcn_permlane32_swap)
    u32x2 r = __builtin_amdgcn_permlane32_swap(a, b, false, false);
    lo = r.x; hi = r.y;
#else
    const int ishi = (threadIdx.x & 63) >> 5;
    unsigned pa = __shfl_xor(a, 32, 64), pb = __shfl_xor(b, 32, 64);
    lo = ishi ? pb : a;
    hi = ishi ? b : pa;
#endif
}

#define GLOBAL_AS __attribute__((address_space(1)))
#define LDS_AS    __attribute__((address_space(3)))

// ---------------------------------------------------------------------------
// Kernel 0: weight preconversion.
// Wt3[m][h][e][d] = W_m[h][d][e] as bf16;  Wpt[e][c] = Wp[c][e] as bf16.
// ---------------------------------------------------------------------------
__global__ __launch_bounds__(256) void wconv_kernel(
    const float* __restrict__ Wq, const float* __restrict__ Wk, const float* __restrict__ Wv,
    const float* __restrict__ Wp,
    unsigned short* __restrict__ Wt3, unsigned short* __restrict__ Wpt)
{
    const int idx = blockIdx.x * 256 + threadIdx.x;
    if (idx < 49152) {
        const int m = idx >> 14, r = idx & 16383;
        const int h = r >> 12, e = (r >> 6) & 63, d = r & 63;
        const float* W = (m == 0) ? Wq : ((m == 1) ? Wk : Wv);
        Wt3[idx] = f2bf(W[(h << 12) + d * 64 + e]);
    } else {
        const int r = idx - 49152;
        const int e = r >> 8, c = r & 255;
        Wpt[r] = f2bf(Wp[c * 256 + e]);
    }
}

// ---------------------------------------------------------------------------
// Kernel 1: QKV projection MFMA GEMM. W staged bf16 via global_load_lds
// (pre-swizzled source, linear LDS dest). Q,K -> [bh][n][d]; V -> [bh][d][n].
// ---------------------------------------------------------------------------
__global__ __launch_bounds__(256) void qkv_kernel(
    const float* __restrict__ x,
    const unsigned short* __restrict__ Wt3,
    const float* __restrict__ bq, const float* __restrict__ bk, const float* __restrict__ bv,
    unsigned short* __restrict__ Qb, unsigned short* __restrict__ Kb,
    unsigned short* __restrict__ Vt)
{
    const int h = blockIdx.x & 3;
    const int tt = blockIdx.x >> 2;
    const int tok0 = tt * 64;
    const int t = threadIdx.x, l = t & 63, w = t >> 6;
    const int lg = l >> 4, lc = l & 15;

    __shared__ uint4 Xs[64 * 8];        // 8 KB  [tok][d-chunk^]
    __shared__ uint4 Ws[3 * 512];       // 24 KB [m][e][d-chunk^]
    __shared__ uint4 Os[64 * 8];        // 8 KB  repack buffer

    // ---- stage W (bf16, pre-transposed): 1536 slots of 16B, 6 per thread
#pragma unroll
    for (int k = 0; k < 6; ++k) {
        const int s = k * 256 + t;
        const int m = s >> 9, sm = s & 511;
        const int e = sm >> 3, cp = sm & 7;
        __builtin_amdgcn_global_load_lds(
            (const GLOBAL_AS unsigned int*)(Wt3 + (m << 14) + (h << 12) + (e << 6) + ((cp ^ (e & 7)) << 3)),
            (LDS_AS unsigned int*)((char*)Ws + (k * 256 + w * 64) * 16),
            16, 0, 0);
    }

    // ---- stage x tile -> bf16 via VALU pack (fp32 source)
    {
        const int r = t >> 2, c4 = t & 3;
        const float* src = x + (size_t)(tok0 + r) * HD + h * Dv + c4 * 16;
        float f[16];
        *(float4*)(f)      = *(const float4*)(src);
        *(float4*)(f + 4)  = *(const float4*)(src + 4);
        *(float4*)(f + 8)  = *(const float4*)(src + 8);
        *(float4*)(f + 12) = *(const float4*)(src + 12);
        Xs[r * 8 + ((c4 * 2)     ^ (r & 7))] = pack8(f);
        Xs[r * 8 + ((c4 * 2 + 1) ^ (r & 7))] = pack8(f + 8);
    }
    asm volatile("s_waitcnt vmcnt(0)" ::: "memory");
    __syncthreads();

    const int ar = w * 16 + lc;
    bf16x8 a[2];
    a[0] = ((const bf16x8*)Xs)[ar * 8 + (lg       ^ (ar & 7))];
    a[1] = ((const bf16x8*)Xs)[ar * 8 + ((4 + lg) ^ (ar & 7))];

    f32x4 acc[3][4];
#pragma unroll
    for (int m = 0; m < 3; ++m)
#pragma unroll
        for (int nt = 0; nt < 4; ++nt) acc[m][nt] = (f32x4){0.f, 0.f, 0.f, 0.f};

#pragma unroll
    for (int kk = 0; kk < 2; ++kk) {
#pragma unroll
        for (int m = 0; m < 3; ++m) {
#pragma unroll
            for (int nt = 0; nt < 4; ++nt) {
                const int br = nt * 16 + lc;
                const bf16x8 b = ((const bf16x8*)Ws)[(m << 9) + br * 8 + ((kk * 4 + lg) ^ (br & 7))];
                acc[m][nt] = __builtin_amdgcn_mfma_f32_16x16x32_bf16(a[kk], b, acc[m][nt], 0, 0, 0);
            }
        }
    }

    const int b_ = tok0 >> 11, n_ = tok0 & (Nv - 1);
    const int bh = b_ * Hv + h;
    unsigned short* Os16 = (unsigned short*)Os;
    const float* biases[3] = {bq + h * Dv, bk + h * Dv, bv + h * Dv};
    const float QSCALE = 0.125f * 1.44269504088896340736f;

#pragma unroll
    for (int m = 0; m < 3; ++m) {
        if (m) __syncthreads();
        if (m < 2) {
#pragma unroll
            for (int nt = 0; nt < 4; ++nt) {
                const int e = nt * 16 + lc;
                const float bias = biases[m][e];
#pragma unroll
                for (int j = 0; j < 4; ++j) {
                    float v = acc[m][nt][j] + bias;
                    if (m == 0) v *= QSCALE;
                    const int row = w * 16 + lg * 4 + j;
                    const int ch = (e >> 3) ^ (row & 7);
                    Os16[row * 64 + ch * 8 + (e & 7)] = f2bf(v);
                }
            }
            __syncthreads();
            const int r = t >> 2, c4 = t & 3;
            unsigned short* dst = (m == 0 ? Qb : Kb) + ((size_t)bh * Nv + n_ + r) * Dv + c4 * 16;
            *(uint4*)dst       = Os[r * 8 + ((c4 * 2)     ^ (r & 7))];
            *(uint4*)(dst + 8) = Os[r * 8 + ((c4 * 2 + 1) ^ (r & 7))];
        } else {
#pragma unroll
            for (int nt = 0; nt < 4; ++nt) {
                const int e = nt * 16 + lc;
                const float bias = biases[2][e];
#pragma unroll
                for (int j = 0; j < 4; ++j) {
                    const int tok = w * 16 + lg * 4 + j;
                    const int ch = (tok >> 3) ^ (e & 7);
                    Os16[e * 64 + ch * 8 + (tok & 7)] = f2bf(acc[2][nt][j] + bias);
                }
            }
            __syncthreads();
            const int e = t >> 2, c4 = t & 3;
            unsigned short* dst = Vt + ((size_t)bh * Dv + e) * Nv + n_ + c4 * 16;
            *(uint4*)dst       = Os[e * 8 + ((c4 * 2)     ^ (e & 7))];
            *(uint4*)(dst + 8) = Os[e * 8 + ((c4 * 2 + 1) ^ (e & 7))];
        }
    }
}

// ---------------------------------------------------------------------------
// Kernel 2: flash attention (round-3 structure); epilogue writes bf16 O.
// ---------------------------------------------------------------------------
__global__ __launch_bounds__(256, 2) void attn_kernel(
    const unsigned short* __restrict__ Qb, const unsigned short* __restrict__ Kb,
    const unsigned short* __restrict__ Vt, unsigned short* __restrict__ Ob)
{
    const int bh = blockIdx.x & 31;
    const int qt = blockIdx.x >> 5;
    const int t = threadIdx.x, w = t >> 6, l = t & 63;
    const int hi = l >> 5, lc = l & 31;

    __shared__ uint4 Ks[2][128 * 8];
    __shared__ uint4 Vs[2][64 * 16];

    const unsigned short* Kg = Kb + (size_t)bh * Nv * Dv;
    const unsigned short* Vg = Vt + (size_t)bh * Dv * Nv;

    const int q_ = qt * 128 + w * 32 + lc;
    const unsigned short* Qrow = Qb + ((size_t)bh * Nv + q_) * Dv;
    bf16x8 qf[4];
#pragma unroll
    for (int kk = 0; kk < 4; ++kk)
        qf[kk] = *(const bf16x8*)(Qrow + kk * 16 + hi * 8);

    auto stage = [&](int buf, int kt) {
#pragma unroll
        for (int k = 0; k < 4; ++k) {
            const int s = k * 256 + t;
            const int base = k * 256 + w * 64;
            {
                const int r = s >> 3, c = (s & 7) ^ (r & 7);
                __builtin_amdgcn_global_load_lds(
                    (const GLOBAL_AS unsigned int*)(Kg + ((size_t)kt * 128 + r) * Dv + c * 8),
                    (LDS_AS unsigned int*)((char*)&Ks[buf][0] + base * 16),
                    16, 0, 0);
            }
            {
                const int r = s >> 4, c = (s & 15) ^ (r & 15);
                __builtin_amdgcn_global_load_lds(
                    (const GLOBAL_AS unsigned int*)(Vg + (size_t)r * Nv + kt * 128 + c * 8),
                    (LDS_AS unsigned int*)((char*)&Vs[buf][0] + base * 16),
                    16, 0, 0);
            }
        }
    };

    f32x16 o0, o1;
#pragma unroll
    for (int i = 0; i < 16; ++i) { o0[i] = 0.f; o1[i] = 0.f; }
    float m_run = -1e30f, l_part = 0.f;

    stage(0, 0);
    asm volatile("s_waitcnt vmcnt(0)" ::: "memory");
    __syncthreads();

    int cur = 0;
    for (int kt = 0; kt < Nv / 128; ++kt) {
        if (kt < Nv / 128 - 1) stage(cur ^ 1, kt + 1);

        const uint4* KsB = &Ks[cur][0];
        const uint4* VsB = &Vs[cur][0];

        f32x16 s4[4];
#pragma unroll
        for (int nt = 0; nt < 4; ++nt) {
#pragma unroll
            for (int i = 0; i < 16; ++i) s4[nt][i] = 0.f;
        }
#pragma unroll
        for (int kk = 0; kk < 4; ++kk) {
#pragma unroll
            for (int nt = 0; nt < 4; ++nt) {
                const int r = nt * 32 + lc;
                const bf16x8 af = *(const bf16x8*)&KsB[r * 8 + ((kk * 2 + hi) ^ (r & 7))];
                s4[nt] = __builtin_amdgcn_mfma_f32_32x32x16_bf16(af, qf[kk], s4[nt], 0, 0, 0);
            }
        }

        float v16[16];
#pragma unroll
        for (int r = 0; r < 16; ++r)
            v16[r] = fmaxf(fmaxf(s4[0][r], s4[1][r]), fmaxf(s4[2][r], s4[3][r]));
#pragma unroll
        for (int st = 8; st; st >>= 1)
#pragma unroll
            for (int r = 0; r < st; ++r) v16[r] = fmaxf(v16[r], v16[r + st]);
        float tm = fmaxf(v16[0], __shfl_xor(v16[0], 32, 64));

        if (!__all(tm <= m_run + 8.f)) {
            const float m_new = fmaxf(m_run, tm);
            const float sc = EXP2(m_run - m_new);
            m_run = m_new;
            l_part *= sc;
#pragma unroll
            for (int i = 0; i < 16; ++i) { o0[i] *= sc; o1[i] *= sc; }
        }

        float tsa[4] = {0.f, 0.f, 0.f, 0.f};
#pragma unroll
        for (int nt = 0; nt < 4; ++nt) {
#pragma unroll
            for (int r = 0; r < 16; ++r) {
                const float p = EXP2(s4[nt][r] - m_run);
                s4[nt][r] = p;
                tsa[r & 3] += p;
            }
            unsigned c[8];
#pragma unroll
            for (int i = 0; i < 8; ++i) c[i] = pk_bf16(s4[nt][2 * i], s4[nt][2 * i + 1]);

            unsigned d0a, d2a, d1a, d3a, d0b, d2b, d1b, d3b;
            swap32(c[0], c[2], d0a, d2a);
            swap32(c[1], c[3], d1a, d3a);
            swap32(c[4], c[6], d0b, d2b);
            swap32(c[5], c[7], d1b, d3b);

            union { unsigned u[4]; bf16x8 v; } pf0, pf1;
            pf0.u[0] = d0a; pf0.u[1] = d1a; pf0.u[2] = d2a; pf0.u[3] = d3a;
            pf1.u[0] = d0b; pf1.u[1] = d1b; pf1.u[2] = d2b; pf1.u[3] = d3b;

#pragma unroll
            for (int kslow = 0; kslow < 2; ++kslow) {
                const bf16x8 pf = kslow ? pf1.v : pf0.v;
                {
                    const int row = lc;
                    const int ch = (nt * 4 + kslow * 2 + hi) ^ (row & 15);
                    const bf16x8 vf = *(const bf16x8*)&VsB[row * 16 + ch];
                    o0 = __builtin_amdgcn_mfma_f32_32x32x16_bf16(vf, pf, o0, 0, 0, 0);
                }
                {
                    const int row = 32 + lc;
                    const int ch = (nt * 4 + kslow * 2 + hi) ^ (row & 15);
                    const bf16x8 vf = *(const bf16x8*)&VsB[row * 16 + ch];
                    o1 = __builtin_amdgcn_mfma_f32_32x32x16_bf16(vf, pf, o1, 0, 0, 0);
                }
            }
        }
        l_part += (tsa[0] + tsa[1]) + (tsa[2] + tsa[3]);

        if (kt < Nv / 128 - 1) {
            asm volatile("s_waitcnt vmcnt(0)" ::: "memory");
            __syncthreads();
            cur ^= 1;
        }
    }

    const float lf = l_part + __shfl_xor(l_part, 32, 64);
    const float inv = 1.0f / lf;
    const int b_ = bh >> 2, h_ = bh & 3;
    unsigned short* orow = Ob + ((size_t)b_ * Nv + q_) * HD + h_ * Dv;
#pragma unroll
    for (int g = 0; g < 4; ++g) {
        uint2 ua, ub;
        ua.x = pk_bf16(o0[g * 4 + 0] * inv, o0[g * 4 + 1] * inv);
        ua.y = pk_bf16(o0[g * 4 + 2] * inv, o0[g * 4 + 3] * inv);
        ub.x = pk_bf16(o1[g * 4 + 0] * inv, o1[g * 4 + 1] * inv);
        ub.y = pk_bf16(o1[g * 4 + 2] * inv, o1[g * 4 + 3] * inv);
        *(uint2*)(orow + 8 * g + 4 * hi)      = ua;
        *(uint2*)(orow + 32 + 8 * g + 4 * hi) = ub;
    }
}

// ---------------------------------------------------------------------------
// Kernel 3: output projection MFMA GEMM. Block = 64 tokens x 256 outs.
// ---------------------------------------------------------------------------
__global__ __launch_bounds__(256) void proj_kernel(
    const unsigned short* __restrict__ Ob, const unsigned short* __restrict__ Wpt,
    const float* __restrict__ bp, float* __restrict__ out)
{
    const int tok0 = blockIdx.x * 64;
    const int t = threadIdx.x, w = t >> 6, l = t & 63;
    const int hi = l >> 5, lc = l & 31;
    const int tw = w >> 1;

    __shared__ uint4 SH[2560];          // 40 KB: [0,512) O-tile, [512,2560) Wpt-slice

    f32x16 acc[4];
#pragma unroll
    for (int ct = 0; ct < 4; ++ct)
#pragma unroll
        for (int i = 0; i < 16; ++i) acc[ct][i] = 0.f;

    for (int kt = 0; kt < 4; ++kt) {
        const int c0 = kt * 64;
        if (kt) __syncthreads();
#pragma unroll
        for (int j = 0; j < 10; ++j) {
            const int s = j * 256 + t;
            const int base = j * 256 + w * 64;
            if (s < 512) {
                const int r = s >> 3, cp = s & 7;
                __builtin_amdgcn_global_load_lds(
                    (const GLOBAL_AS unsigned int*)(Ob + (size_t)(tok0 + r) * HD + c0 + ((cp ^ (r & 7)) << 3)),
                    (LDS_AS unsigned int*)((char*)SH + base * 16),
                    16, 0, 0);
            } else {
                const int sm = s - 512;
                const int e = sm >> 3, cp = sm & 7;
                __builtin_amdgcn_global_load_lds(
                    (const GLOBAL_AS unsigned int*)(Wpt + (size_t)e * HD + c0 + ((cp ^ (e & 7)) << 3)),
                    (LDS_AS unsigned int*)((char*)SH + base * 16),
                    16, 0, 0);
            }
        }
        asm volatile("s_waitcnt vmcnt(0)" ::: "memory");
        __syncthreads();

        const bf16x8* Osh = (const bf16x8*)SH;
        const bf16x8* Wsh = (const bf16x8*)(SH + 512);
        const int r = tw * 32 + lc;
#pragma unroll
        for (int kk = 0; kk < 4; ++kk) {
            const bf16x8 af = Osh[r * 8 + ((kk * 2 + hi) ^ (r & 7))];
#pragma unroll
            for (int ct = 0; ct < 4; ++ct) {
                const int e = (w & 1) * 128 + ct * 32 + lc;
                const bf16x8 bf = Wsh[e * 8 + ((kk * 2 + hi) ^ (e & 7))];
                acc[ct] = __builtin_amdgcn_mfma_f32_32x32x16_bf16(af, bf, acc[ct], 0, 0, 0);
            }
        }
    }

#pragma unroll
    for (int ct = 0; ct < 4; ++ct) {
        const int e = (w & 1) * 128 + ct * 32 + lc;
        const float bias = bp[e];
#pragma unroll
        for (int r = 0; r < 16; ++r) {
            const int tok = tok0 + tw * 32 + (r & 3) + 8 * (r >> 2) + 4 * hi;
            out[(size_t)tok * OUTv + e] = acc[ct][r] + bias;
        }
    }
}

// ---------------------------------------------------------------------------
extern "C" void kernel_launch(void* const* d_in, const int* in_sizes, int n_in,
                              void* d_out, int out_size, void* d_ws, size_t ws_size,
                              hipStream_t stream)
{
    const float* x  = (const float*)d_in[0];
    const float* Wq = (const float*)d_in[1];
    const float* Wk = (const float*)d_in[2];
    const float* Wv = (const float*)d_in[3];
    const float* bq = (const float*)d_in[4];
    const float* bk = (const float*)d_in[5];
    const float* bv = (const float*)d_in[6];
    const float* Wp = (const float*)d_in[7];
    const float* bp = (const float*)d_in[8];
    float* out = (float*)d_out;

    unsigned short* us = (unsigned short*)d_ws;
    unsigned short* Qb  = us;
    unsigned short* Kb  = us + PH;
    unsigned short* Vt  = us + 2 * PH;
    unsigned short* Ob  = us + 3 * PH;
    unsigned short* Wt3 = us + 4 * PH;
    unsigned short* Wpt = Wt3 + 49152;

    wconv_kernel<<<448, 256, 0, stream>>>(Wq, Wk, Wv, Wp, Wt3, Wpt);
    qkv_kernel<<<(Bv * Nv / 64) * Hv, 256, 0, stream>>>(x, Wt3, bq, bk, bv, Qb, Kb, Vt);
    attn_kernel<<<(Nv / 128) * BH, 256, 0, stream>>>(Qb, Kb, Vt, Ob);
    proj_kernel<<<Bv * Nv / 64, 256, 0, stream>>>(Ob, Wpt, bp, out);
}

// Round 6
// 154.624 us; speedup vs baseline: 47.4858x; 1.0087x over previous
//
#include <hip/hip_runtime.h>

typedef __attribute__((ext_vector_type(4)))  float  f32x4;
typedef __attribute__((ext_vector_type(16))) float  f32x16;
typedef __attribute__((ext_vector_type(8)))  __bf16 bf16x8;
typedef __attribute__((ext_vector_type(2)))  unsigned u32x2;

constexpr int Bv = 8, Nv = 2048, Hv = 4, Dv = 64, OUTv = 256, HD = 256;
constexpr int BH = Bv * Hv;                      // 32
constexpr size_t PH = (size_t)BH * Nv * Dv;      // elements per [bh][n][d] buffer

#if __has_builtin(__builtin_amdgcn_exp2f)
#define EXP2(x) __builtin_amdgcn_exp2f(x)
#else
#define EXP2(x) exp2f(x)
#endif

// native bf16 conversions -> compiler emits v_cvt_pk_bf16_f32 (RNE), 1 op/pair
__device__ __forceinline__ unsigned short f2bf(float f) {
    union { __bf16 h; unsigned short u; } r;
    r.h = (__bf16)f;
    return r.u;
}

__device__ __forceinline__ unsigned pk_bf16(float a, float b) {
    union { __bf16 h[2]; unsigned u; } r;
    r.h[0] = (__bf16)a; r.h[1] = (__bf16)b;
    return r.u;
}

__device__ __forceinline__ uint4 pack8(const float* f) {
    uint4 u;
    u.x = pk_bf16(f[0], f[1]);
    u.y = pk_bf16(f[2], f[3]);
    u.z = pk_bf16(f[4], f[5]);
    u.w = pk_bf16(f[6], f[7]);
    return u;
}

__device__ __forceinline__ void swap32(unsigned a, unsigned b, unsigned& lo, unsigned& hi) {
#if __has_builtin(__builtin_amdgcn_permlane32_swap)
    u32x2 r = __builtin_amdgcn_permlane32_swap(a, b, false, false);
    lo = r.x; hi = r.y;
#else
    const int ishi = (threadIdx.x & 63) >> 5;
    unsigned pa = __shfl_xor(a, 32, 64), pb = __shfl_xor(b, 32, 64);
    lo = ishi ? pb : a;
    hi = ishi ? b : pa;
#endif
}

#define GLOBAL_AS __attribute__((address_space(1)))
#define LDS_AS    __attribute__((address_space(3)))

// ---------------------------------------------------------------------------
// Kernel 0: weight preconversion.
// Wt3[m][h][e][d] = W_m[h][d][e] as bf16;  Wpt[e][c] = Wp[c][e] as bf16.
// ---------------------------------------------------------------------------
__global__ __launch_bounds__(256) void wconv_kernel(
    const float* __restrict__ Wq, const float* __restrict__ Wk, const float* __restrict__ Wv,
    const float* __restrict__ Wp,
    unsigned short* __restrict__ Wt3, unsigned short* __restrict__ Wpt)
{
    const int idx = blockIdx.x * 256 + threadIdx.x;
    if (idx < 49152) {
        const int m = idx >> 14, r = idx & 16383;
        const int h = r >> 12, e = (r >> 6) & 63, d = r & 63;
        const float* W = (m == 0) ? Wq : ((m == 1) ? Wk : Wv);
        Wt3[idx] = f2bf(W[(h << 12) + d * 64 + e]);
    } else {
        const int r = idx - 49152;
        const int e = r >> 8, c = r & 255;
        Wpt[r] = f2bf(Wp[c * 256 + e]);
    }
}

// ---------------------------------------------------------------------------
// Kernel 1: QKV projection MFMA GEMM. W staged bf16 via global_load_lds
// (pre-swizzled source, linear LDS dest). Q,K -> [bh][n][d]; V -> [bh][d][n].
// ---------------------------------------------------------------------------
__global__ __launch_bounds__(256) void qkv_kernel(
    const float* __restrict__ x,
    const unsigned short* __restrict__ Wt3,
    const float* __restrict__ bq, const float* __restrict__ bk, const float* __restrict__ bv,
    unsigned short* __restrict__ Qb, unsigned short* __restrict__ Kb,
    unsigned short* __restrict__ Vt)
{
    const int h = blockIdx.x & 3;
    const int tt = blockIdx.x >> 2;
    const int tok0 = tt * 64;
    const int t = threadIdx.x, l = t & 63, w = t >> 6;
    const int lg = l >> 4, lc = l & 15;

    __shared__ uint4 Xs[64 * 8];        // 8 KB  [tok][d-chunk^]
    __shared__ uint4 Ws[3 * 512];       // 24 KB [m][e][d-chunk^]
    __shared__ uint4 Os[64 * 8];        // 8 KB  repack buffer

    // ---- stage W (bf16, pre-transposed): 1536 slots of 16B, 6 per thread
#pragma unroll
    for (int k = 0; k < 6; ++k) {
        const int s = k * 256 + t;
        const int m = s >> 9, sm = s & 511;
        const int e = sm >> 3, cp = sm & 7;
        __builtin_amdgcn_global_load_lds(
            (const GLOBAL_AS unsigned int*)(Wt3 + (m << 14) + (h << 12) + (e << 6) + ((cp ^ (e & 7)) << 3)),
            (LDS_AS unsigned int*)((char*)Ws + (k * 256 + w * 64) * 16),
            16, 0, 0);
    }

    // ---- stage x tile -> bf16 via VALU pack (fp32 source)
    {
        const int r = t >> 2, c4 = t & 3;
        const float* src = x + (size_t)(tok0 + r) * HD + h * Dv + c4 * 16;
        float f[16];
        *(float4*)(f)      = *(const float4*)(src);
        *(float4*)(f + 4)  = *(const float4*)(src + 4);
        *(float4*)(f + 8)  = *(const float4*)(src + 8);
        *(float4*)(f + 12) = *(const float4*)(src + 12);
        Xs[r * 8 + ((c4 * 2)     ^ (r & 7))] = pack8(f);
        Xs[r * 8 + ((c4 * 2 + 1) ^ (r & 7))] = pack8(f + 8);
    }
    asm volatile("s_waitcnt vmcnt(0)" ::: "memory");
    __syncthreads();

    const int ar = w * 16 + lc;
    bf16x8 a[2];
    a[0] = ((const bf16x8*)Xs)[ar * 8 + (lg       ^ (ar & 7))];
    a[1] = ((const bf16x8*)Xs)[ar * 8 + ((4 + lg) ^ (ar & 7))];

    f32x4 acc[3][4];
#pragma unroll
    for (int m = 0; m < 3; ++m)
#pragma unroll
        for (int nt = 0; nt < 4; ++nt) acc[m][nt] = (f32x4){0.f, 0.f, 0.f, 0.f};

#pragma unroll
    for (int kk = 0; kk < 2; ++kk) {
#pragma unroll
        for (int m = 0; m < 3; ++m) {
#pragma unroll
            for (int nt = 0; nt < 4; ++nt) {
                const int br = nt * 16 + lc;
                const bf16x8 b = ((const bf16x8*)Ws)[(m << 9) + br * 8 + ((kk * 4 + lg) ^ (br & 7))];
                acc[m][nt] = __builtin_amdgcn_mfma_f32_16x16x32_bf16(a[kk], b, acc[m][nt], 0, 0, 0);
            }
        }
    }

    const int b_ = tok0 >> 11, n_ = tok0 & (Nv - 1);
    const int bh = b_ * Hv + h;
    unsigned short* Os16 = (unsigned short*)Os;
    const float* biases[3] = {bq + h * Dv, bk + h * Dv, bv + h * Dv};
    const float QSCALE = 0.125f * 1.44269504088896340736f;

#pragma unroll
    for (int m = 0; m < 3; ++m) {
        if (m) __syncthreads();
        if (m < 2) {
#pragma unroll
            for (int nt = 0; nt < 4; ++nt) {
                const int e = nt * 16 + lc;
                const float bias = biases[m][e];
#pragma unroll
                for (int j = 0; j < 4; ++j) {
                    float v = acc[m][nt][j] + bias;
                    if (m == 0) v *= QSCALE;
                    const int row = w * 16 + lg * 4 + j;
                    const int ch = (e >> 3) ^ (row & 7);
                    Os16[row * 64 + ch * 8 + (e & 7)] = f2bf(v);
                }
            }
            __syncthreads();
            const int r = t >> 2, c4 = t & 3;
            unsigned short* dst = (m == 0 ? Qb : Kb) + ((size_t)bh * Nv + n_ + r) * Dv + c4 * 16;
            *(uint4*)dst       = Os[r * 8 + ((c4 * 2)     ^ (r & 7))];
            *(uint4*)(dst + 8) = Os[r * 8 + ((c4 * 2 + 1) ^ (r & 7))];
        } else {
#pragma unroll
            for (int nt = 0; nt < 4; ++nt) {
                const int e = nt * 16 + lc;
                const float bias = biases[2][e];
#pragma unroll
                for (int j = 0; j < 4; ++j) {
                    const int tok = w * 16 + lg * 4 + j;
                    const int ch = (tok >> 3) ^ (e & 7);
                    Os16[e * 64 + ch * 8 + (tok & 7)] = f2bf(acc[2][nt][j] + bias);
                }
            }
            __syncthreads();
            const int e = t >> 2, c4 = t & 3;
            unsigned short* dst = Vt + ((size_t)bh * Dv + e) * Nv + n_ + c4 * 16;
            *(uint4*)dst       = Os[e * 8 + ((c4 * 2)     ^ (e & 7))];
            *(uint4*)(dst + 8) = Os[e * 8 + ((c4 * 2 + 1) ^ (e & 7))];
        }
    }
}

// ---------------------------------------------------------------------------
// Kernel 2: flash attention (round-3 structure); native cvt_pk packing,
// setprio around MFMA clusters; bf16 O epilogue.
// ---------------------------------------------------------------------------
__global__ __launch_bounds__(256, 2) void attn_kernel(
    const unsigned short* __restrict__ Qb, const unsigned short* __restrict__ Kb,
    const unsigned short* __restrict__ Vt, unsigned short* __restrict__ Ob)
{
    const int bh = blockIdx.x & 31;
    const int qt = blockIdx.x >> 5;
    const int t = threadIdx.x, w = t >> 6, l = t & 63;
    const int hi = l >> 5, lc = l & 31;

    __shared__ uint4 Ks[2][128 * 8];
    __shared__ uint4 Vs[2][64 * 16];

    const unsigned short* Kg = Kb + (size_t)bh * Nv * Dv;
    const unsigned short* Vg = Vt + (size_t)bh * Dv * Nv;

    const int q_ = qt * 128 + w * 32 + lc;
    const unsigned short* Qrow = Qb + ((size_t)bh * Nv + q_) * Dv;
    bf16x8 qf[4];
#pragma unroll
    for (int kk = 0; kk < 4; ++kk)
        qf[kk] = *(const bf16x8*)(Qrow + kk * 16 + hi * 8);

    auto stage = [&](int buf, int kt) {
#pragma unroll
        for (int k = 0; k < 4; ++k) {
            const int s = k * 256 + t;
            const int base = k * 256 + w * 64;
            {
                const int r = s >> 3, c = (s & 7) ^ (r & 7);
                __builtin_amdgcn_global_load_lds(
                    (const GLOBAL_AS unsigned int*)(Kg + ((size_t)kt * 128 + r) * Dv + c * 8),
                    (LDS_AS unsigned int*)((char*)&Ks[buf][0] + base * 16),
                    16, 0, 0);
            }
            {
                const int r = s >> 4, c = (s & 15) ^ (r & 15);
                __builtin_amdgcn_global_load_lds(
                    (const GLOBAL_AS unsigned int*)(Vg + (size_t)r * Nv + kt * 128 + c * 8),
                    (LDS_AS unsigned int*)((char*)&Vs[buf][0] + base * 16),
                    16, 0, 0);
            }
        }
    };

    f32x16 o0, o1;
#pragma unroll
    for (int i = 0; i < 16; ++i) { o0[i] = 0.f; o1[i] = 0.f; }
    float m_run = -1e30f, l_part = 0.f;

    stage(0, 0);
    asm volatile("s_waitcnt vmcnt(0)" ::: "memory");
    __syncthreads();

    int cur = 0;
    for (int kt = 0; kt < Nv / 128; ++kt) {
        if (kt < Nv / 128 - 1) stage(cur ^ 1, kt + 1);

        const uint4* KsB = &Ks[cur][0];
        const uint4* VsB = &Vs[cur][0];

        f32x16 s4[4];
#pragma unroll
        for (int nt = 0; nt < 4; ++nt) {
#pragma unroll
            for (int i = 0; i < 16; ++i) s4[nt][i] = 0.f;
        }
        __builtin_amdgcn_s_setprio(1);
#pragma unroll
        for (int kk = 0; kk < 4; ++kk) {
#pragma unroll
            for (int nt = 0; nt < 4; ++nt) {
                const int r = nt * 32 + lc;
                const bf16x8 af = *(const bf16x8*)&KsB[r * 8 + ((kk * 2 + hi) ^ (r & 7))];
                s4[nt] = __builtin_amdgcn_mfma_f32_32x32x16_bf16(af, qf[kk], s4[nt], 0, 0, 0);
            }
        }
        __builtin_amdgcn_s_setprio(0);

        float v16[16];
#pragma unroll
        for (int r = 0; r < 16; ++r)
            v16[r] = fmaxf(fmaxf(s4[0][r], s4[1][r]), fmaxf(s4[2][r], s4[3][r]));
#pragma unroll
        for (int st = 8; st; st >>= 1)
#pragma unroll
            for (int r = 0; r < st; ++r) v16[r] = fmaxf(v16[r], v16[r + st]);
        float tm = fmaxf(v16[0], __shfl_xor(v16[0], 32, 64));

        if (!__all(tm <= m_run + 8.f)) {
            const float m_new = fmaxf(m_run, tm);
            const float sc = EXP2(m_run - m_new);
            m_run = m_new;
            l_part *= sc;
#pragma unroll
            for (int i = 0; i < 16; ++i) { o0[i] *= sc; o1[i] *= sc; }
        }

        float tsa[4] = {0.f, 0.f, 0.f, 0.f};
#pragma unroll
        for (int nt = 0; nt < 4; ++nt) {
#pragma unroll
            for (int r = 0; r < 16; ++r) {
                const float p = EXP2(s4[nt][r] - m_run);
                s4[nt][r] = p;
                tsa[r & 3] += p;
            }
            unsigned c[8];
#pragma unroll
            for (int i = 0; i < 8; ++i) c[i] = pk_bf16(s4[nt][2 * i], s4[nt][2 * i + 1]);

            unsigned d0a, d2a, d1a, d3a, d0b, d2b, d1b, d3b;
            swap32(c[0], c[2], d0a, d2a);
            swap32(c[1], c[3], d1a, d3a);
            swap32(c[4], c[6], d0b, d2b);
            swap32(c[5], c[7], d1b, d3b);

            union { unsigned u[4]; bf16x8 v; } pf0, pf1;
            pf0.u[0] = d0a; pf0.u[1] = d1a; pf0.u[2] = d2a; pf0.u[3] = d3a;
            pf1.u[0] = d0b; pf1.u[1] = d1b; pf1.u[2] = d2b; pf1.u[3] = d3b;

            __builtin_amdgcn_s_setprio(1);
#pragma unroll
            for (int kslow = 0; kslow < 2; ++kslow) {
                const bf16x8 pf = kslow ? pf1.v : pf0.v;
                {
                    const int row = lc;
                    const int ch = (nt * 4 + kslow * 2 + hi) ^ (row & 15);
                    const bf16x8 vf = *(const bf16x8*)&VsB[row * 16 + ch];
                    o0 = __builtin_amdgcn_mfma_f32_32x32x16_bf16(vf, pf, o0, 0, 0, 0);
                }
                {
                    const int row = 32 + lc;
                    const int ch = (nt * 4 + kslow * 2 + hi) ^ (row & 15);
                    const bf16x8 vf = *(const bf16x8*)&VsB[row * 16 + ch];
                    o1 = __builtin_amdgcn_mfma_f32_32x32x16_bf16(vf, pf, o1, 0, 0, 0);
                }
            }
            __builtin_amdgcn_s_setprio(0);
        }
        l_part += (tsa[0] + tsa[1]) + (tsa[2] + tsa[3]);

        if (kt < Nv / 128 - 1) {
            asm volatile("s_waitcnt vmcnt(0)" ::: "memory");
            __syncthreads();
            cur ^= 1;
        }
    }

    const float lf = l_part + __shfl_xor(l_part, 32, 64);
    const float inv = 1.0f / lf;
    const int b_ = bh >> 2, h_ = bh & 3;
    unsigned short* orow = Ob + ((size_t)b_ * Nv + q_) * HD + h_ * Dv;
#pragma unroll
    for (int g = 0; g < 4; ++g) {
        uint2 ua, ub;
        ua.x = pk_bf16(o0[g * 4 + 0] * inv, o0[g * 4 + 1] * inv);
        ua.y = pk_bf16(o0[g * 4 + 2] * inv, o0[g * 4 + 3] * inv);
        ub.x = pk_bf16(o1[g * 4 + 0] * inv, o1[g * 4 + 1] * inv);
        ub.y = pk_bf16(o1[g * 4 + 2] * inv, o1[g * 4 + 3] * inv);
        *(uint2*)(orow + 8 * g + 4 * hi)      = ua;
        *(uint2*)(orow + 32 + 8 * g + 4 * hi) = ub;
    }
}

// ---------------------------------------------------------------------------
// Kernel 3: output projection MFMA GEMM. Block = 64 tokens x 256 outs.
// ---------------------------------------------------------------------------
__global__ __launch_bounds__(256) void proj_kernel(
    const unsigned short* __restrict__ Ob, const unsigned short* __restrict__ Wpt,
    const float* __restrict__ bp, float* __restrict__ out)
{
    const int tok0 = blockIdx.x * 64;
    const int t = threadIdx.x, w = t >> 6, l = t & 63;
    const int hi = l >> 5, lc = l & 31;
    const int tw = w >> 1;

    __shared__ uint4 SH[2560];          // 40 KB: [0,512) O-tile, [512,2560) Wpt-slice

    f32x16 acc[4];
#pragma unroll
    for (int ct = 0; ct < 4; ++ct)
#pragma unroll
        for (int i = 0; i < 16; ++i) acc[ct][i] = 0.f;

    for (int kt = 0; kt < 4; ++kt) {
        const int c0 = kt * 64;
        if (kt) __syncthreads();
#pragma unroll
        for (int j = 0; j < 10; ++j) {
            const int s = j * 256 + t;
            const int base = j * 256 + w * 64;
            if (s < 512) {
                const int r = s >> 3, cp = s & 7;
                __builtin_amdgcn_global_load_lds(
                    (const GLOBAL_AS unsigned int*)(Ob + (size_t)(tok0 + r) * HD + c0 + ((cp ^ (r & 7)) << 3)),
                    (LDS_AS unsigned int*)((char*)SH + base * 16),
                    16, 0, 0);
            } else {
                const int sm = s - 512;
                const int e = sm >> 3, cp = sm & 7;
                __builtin_amdgcn_global_load_lds(
                    (const GLOBAL_AS unsigned int*)(Wpt + (size_t)e * HD + c0 + ((cp ^ (e & 7)) << 3)),
                    (LDS_AS unsigned int*)((char*)SH + base * 16),
                    16, 0, 0);
            }
        }
        asm volatile("s_waitcnt vmcnt(0)" ::: "memory");
        __syncthreads();

        const bf16x8* Osh = (const bf16x8*)SH;
        const bf16x8* Wsh = (const bf16x8*)(SH + 512);
        const int r = tw * 32 + lc;
#pragma unroll
        for (int kk = 0; kk < 4; ++kk) {
            const bf16x8 af = Osh[r * 8 + ((kk * 2 + hi) ^ (r & 7))];
#pragma unroll
            for (int ct = 0; ct < 4; ++ct) {
                const int e = (w & 1) * 128 + ct * 32 + lc;
                const bf16x8 bf = Wsh[e * 8 + ((kk * 2 + hi) ^ (e & 7))];
                acc[ct] = __builtin_amdgcn_mfma_f32_32x32x16_bf16(af, bf, acc[ct], 0, 0, 0);
            }
        }
    }

#pragma unroll
    for (int ct = 0; ct < 4; ++ct) {
        const int e = (w & 1) * 128 + ct * 32 + lc;
        const float bias = bp[e];
#pragma unroll
        for (int r = 0; r < 16; ++r) {
            const int tok = tok0 + tw * 32 + (r & 3) + 8 * (r >> 2) + 4 * hi;
            out[(size_t)tok * OUTv + e] = acc[ct][r] + bias;
        }
    }
}

// ---------------------------------------------------------------------------
extern "C" void kernel_launch(void* const* d_in, const int* in_sizes, int n_in,
                              void* d_out, int out_size, void* d_ws, size_t ws_size,
                              hipStream_t stream)
{
    const float* x  = (const float*)d_in[0];
    const float* Wq = (const float*)d_in[1];
    const float* Wk = (const float*)d_in[2];
    const float* Wv = (const float*)d_in[3];
    const float* bq = (const float*)d_in[4];
    const float* bk = (const float*)d_in[5];
    const float* bv = (const float*)d_in[6];
    const float* Wp = (const float*)d_in[7];
    const float* bp = (const float*)d_in[8];
    float* out = (float*)d_out;

    unsigned short* us = (unsigned short*)d_ws;
    unsigned short* Qb  = us;
    unsigned short* Kb  = us + PH;
    unsigned short* Vt  = us + 2 * PH;
    unsigned short* Ob  = us + 3 * PH;
    unsigned short* Wt3 = us + 4 * PH;
    unsigned short* Wpt = Wt3 + 49152;

    wconv_kernel<<<448, 256, 0, stream>>>(Wq, Wk, Wv, Wp, Wt3, Wpt);
    qkv_kernel<<<(Bv * Nv / 64) * Hv, 256, 0, stream>>>(x, Wt3, bq, bk, bv, Qb, Kb, Vt);
    attn_kernel<<<(Nv / 128) * BH, 256, 0, stream>>>(Qb, Kb, Vt, Ob);
    proj_kernel<<<Bv * Nv / 64, 256, 0, stream>>>(Ob, Wpt, bp, out);
}